// Round 3
// baseline (311.475 us; speedup 1.0000x reference)
//
#include <hip/hip_runtime.h>
#include <hip/hip_bf16.h>
#include <cstdint>

// ---------------------------------------------------------------------------
// MAB block (f32 in/out, bf16 internal):
//   Qp=(Q@Wq+bq)*Qm; Kp=(K@Wk+bk)*Km; V=K@Wv+bv
//   S = Qh Kh^T / sqrt(512);  X = exp(exp(S)*Km)*Qm;  A = X/(sum+1e-8)
//   O = Qh + A@Vh;  O = LN0(O);  O = O + relu(O@Wo+bo);  out = LN1(O)
//
// R9:  attn 2->4 blocks/CU (sQ dropped). 81 -> 74 us, Occ 20->33.
// R10: attn phase-serialization attack (counters: MFMA 18.5 / VALU 44 /
//      LDS ~33 / HBM 14 -- nothing saturated, wall ~= serial phase sum):
//      (1) T14 async-stage split: K/V/Km staged via regs, next tile's
//          global loads issued right after the staging barrier so L2
//          latency hides under S^T+softmax+PV compute.
//      (2) T5 s_setprio(1) around both MFMA clusters (attn blocks are
//          independent -> +4-7% per m191).
// Buffers: ws ~36MB (T, smalls, masks, Qp, Kp); Qbf borrows Kp slot;
// d_out 32MB: lower=Kbf, upper=Vt (both dead before final LN writes).
// ---------------------------------------------------------------------------

typedef __bf16 bf16;
typedef __bf16 bf16x4 __attribute__((ext_vector_type(4)));
typedef __bf16 bf16x8 __attribute__((ext_vector_type(8)));
typedef float f32x4 __attribute__((ext_vector_type(4)));

#define MFMA16(a, b, c) __builtin_amdgcn_mfma_f32_16x16x32_bf16((a), (b), (c), 0, 0, 0)

#if __has_builtin(__builtin_amdgcn_exp2f)
#define EXP2F(x) __builtin_amdgcn_exp2f(x)
#else
#define EXP2F(x) exp2f(x)
#endif

static __device__ __forceinline__ void async_lds16(const bf16* g, bf16* l) {
  __builtin_amdgcn_global_load_lds(
      (__attribute__((address_space(1))) void*)(void*)g,
      (__attribute__((address_space(3))) void*)l,
      16, 0, 0);
}

// XCD swizzle for 512-block GEMM grids: 4 col-blocks of one row share id&7.
static __device__ __forceinline__ void swz512(int id, long& rowBase, int& colBase) {
  colBase = ((id >> 3) & 3) * 128;
  rowBase = (long)((id & 7) + 8 * (id >> 5)) * 128;
}

// ---------------------------------------------------------------------------
// Weight convert+transpose: T[n][k] = (bf16)W[k][n], 512x512, f32 in.
// ---------------------------------------------------------------------------
__global__ __launch_bounds__(256) void transposeW(
    const float* __restrict__ Wq, const float* __restrict__ Wk,
    const float* __restrict__ Wv, const float* __restrict__ Wo,
    bf16* __restrict__ Tq, bf16* __restrict__ Tk,
    bf16* __restrict__ Tv, bf16* __restrict__ To) {
  const float* src;
  bf16* dst;
  switch (blockIdx.z) {
    case 0: src = Wq; dst = Tq; break;
    case 1: src = Wk; dst = Tk; break;
    case 2: src = Wv; dst = Tv; break;
    default: src = Wo; dst = To; break;
  }
  __shared__ bf16 t[64][72];
  const int tid = threadIdx.x;
  const int n0 = blockIdx.x * 64;
  const int k0 = blockIdx.y * 64;
  for (int c = tid; c < 512; c += 256) {
    const int row = c >> 3, col = (c & 7) * 8;   // row: k, col: n
    const float* sp = src + (size_t)(k0 + row) * 512 + n0 + col;
    const f32x4 a = *(const f32x4*)sp;
    const f32x4 b = *(const f32x4*)(sp + 4);
    bf16x8 v;
#pragma unroll
    for (int j = 0; j < 4; ++j) { v[j] = (bf16)a[j]; v[j + 4] = (bf16)b[j]; }
    *(bf16x8*)(&t[row][col]) = v;
  }
  __syncthreads();
  for (int c = tid; c < 512; c += 256) {
    const int row = c >> 3, col8 = (c & 7) * 8;  // row: n, col8: k
    bf16x8 v;
#pragma unroll
    for (int j = 0; j < 8; ++j) v[j] = t[col8 + j][row];
    *(bf16x8*)(dst + (size_t)(n0 + row) * 512 + k0 + col8) = v;
  }
}

// ---------------------------------------------------------------------------
// Big f32 -> bf16 conversion for Q and K (8.4M elems each; y selects).
// ---------------------------------------------------------------------------
__global__ __launch_bounds__(256) void convertX(
    const float* __restrict__ Q, const float* __restrict__ K,
    bf16* __restrict__ Qb, bf16* __restrict__ Kb) {
  const float* s = blockIdx.y ? K : Q;
  bf16* d = blockIdx.y ? Kb : Qb;
  const long i = ((long)blockIdx.x * 256 + threadIdx.x) * 8;
  const f32x4 x0 = *(const f32x4*)(s + i);
  const f32x4 x1 = *(const f32x4*)(s + i + 4);
  bf16x8 o;
#pragma unroll
  for (int j = 0; j < 4; ++j) { o[j] = (bf16)x0[j]; o[j + 4] = (bf16)x1[j]; }
  *(bf16x8*)(d + i) = o;
}

// ---------------------------------------------------------------------------
// Batched f32->bf16 conversion of 10 small arrays.
// ---------------------------------------------------------------------------
struct ConvArgs {
  const float* src[10];
  bf16* dst[10];
  int n[10];
};

__global__ __launch_bounds__(256) void convert_all(ConvArgs a) {
  const int seg = blockIdx.z;
  const int n = a.n[seg];
  const long i = ((long)blockIdx.x * 256 + threadIdx.x) * 8;
  if (i >= n) return;
  const float* s = a.src[seg];
  const f32x4 x0 = *(const f32x4*)(s + i);
  const f32x4 x1 = *(const f32x4*)(s + i + 4);
  bf16x8 o;
#pragma unroll
  for (int j = 0; j < 4; ++j) { o[j] = (bf16)x0[j]; o[j + 4] = (bf16)x1[j]; }
  *(bf16x8*)(a.dst[seg] + i) = o;
}

// ---------------------------------------------------------------------------
// GEMM (bf16 A): out[M x 512] = epilogue(A @ Bt^T + bias).
//   mask != null : out = (acc+bias) * mask[row]
//   resid != null: out = resid + relu(acc+bias)
// m97 structure; XCD-swizzled linear grid (512 blocks).
// ---------------------------------------------------------------------------
__global__ __launch_bounds__(256, 2) void gemm512(
    const bf16* __restrict__ A, const bf16* __restrict__ Bt,
    const bf16* __restrict__ bias, const bf16* __restrict__ mask,
    const bf16* __restrict__ resid, bf16* __restrict__ out) {
  __shared__ bf16 sA[128 * 32];
  __shared__ bf16 sB[128 * 32];
  const int tid = threadIdx.x;
  const int lane = tid & 63;
  const int w = tid >> 6;
  const int fm = lane & 15;
  const int fq = lane >> 4;
  long rowBase; int colBase;
  swz512(blockIdx.x, rowBase, colBase);

  f32x4 acc[4][4] = {};

  const int c0 = tid, c1 = tid + 256;
  const int r0 = c0 >> 2, o0 = (c0 & 3) * 8;
  const int r1 = c1 >> 2, o1 = (c1 & 3) * 8;
  const bf16* A0 = A + (rowBase + r0) * 512 + o0;
  const bf16* A1 = A + (rowBase + r1) * 512 + o1;
  const bf16* B0 = Bt + (size_t)(colBase + r0) * 512 + o0;
  const bf16* B1 = Bt + (size_t)(colBase + r1) * 512 + o1;

  const int wr = (w & 1) * 64;
  const int wc = (w >> 1) * 64;

  for (int kt = 0; kt < 16; ++kt) {
    const int k0 = kt * 32;
    __syncthreads();
    async_lds16(A0 + k0, sA + c0 * 8);
    async_lds16(A1 + k0, sA + c1 * 8);
    async_lds16(B0 + k0, sB + c0 * 8);
    async_lds16(B1 + k0, sB + c1 * 8);
    __syncthreads();
    bf16x8 a[4], b[4];
#pragma unroll
    for (int i = 0; i < 4; ++i)
      a[i] = *(const bf16x8*)(sA + (wr + i * 16 + fm) * 32 + fq * 8);
#pragma unroll
    for (int j = 0; j < 4; ++j)
      b[j] = *(const bf16x8*)(sB + (wc + j * 16 + fm) * 32 + fq * 8);
#pragma unroll
    for (int i = 0; i < 4; ++i)
#pragma unroll
      for (int j = 0; j < 4; ++j)
        acc[i][j] = MFMA16(a[i], b[j], acc[i][j]);
  }

  // epilogue; C/D layout: col = lane&15, row = (lane>>4)*4 + r
#pragma unroll
  for (int i = 0; i < 4; ++i) {
#pragma unroll
    for (int r = 0; r < 4; ++r) {
      const long R = rowBase + wr + i * 16 + fq * 4 + r;
      const float mk = mask ? (float)mask[R] : 1.0f;
      const bf16* resrow = resid ? resid + R * 512 : nullptr;
      bf16* outrow = out + R * 512;
#pragma unroll
      for (int j = 0; j < 4; ++j) {
        const int C = colBase + wc + j * 16 + fm;
        float v = acc[i][j][r] + (float)bias[C];
        if (mask) v *= mk;
        if (resid) v = (float)resrow[C] + fmaxf(v, 0.0f);
        outrow[C] = (bf16)v;
      }
    }
  }
}

// ---------------------------------------------------------------------------
// Fused K/V projection (bf16 A): one A staging feeds two MFMA chains.
//   Kp[R][C] = (A@Tk^T + bk) * Km[R];  Vt[...] transposed V store.
// ---------------------------------------------------------------------------
__global__ __launch_bounds__(256, 2) void gemmKV(
    const bf16* __restrict__ A, const bf16* __restrict__ Btk,
    const bf16* __restrict__ Btv, const bf16* __restrict__ bk,
    const bf16* __restrict__ bv, const bf16* __restrict__ Km,
    bf16* __restrict__ Kp, bf16* __restrict__ Vt) {
  __shared__ bf16 sA[128 * 32];
  __shared__ bf16 sBk[128 * 32];
  __shared__ bf16 sBv[128 * 32];
  const int tid = threadIdx.x;
  const int lane = tid & 63;
  const int w = tid >> 6;
  const int fm = lane & 15;
  const int fq = lane >> 4;
  long rowBase; int colBase;
  swz512(blockIdx.x, rowBase, colBase);

  f32x4 acck[4][4] = {};
  f32x4 accv[4][4] = {};

  const int c0 = tid, c1 = tid + 256;
  const int r0 = c0 >> 2, o0 = (c0 & 3) * 8;
  const int r1 = c1 >> 2, o1 = (c1 & 3) * 8;
  const bf16* A0 = A + (rowBase + r0) * 512 + o0;
  const bf16* A1 = A + (rowBase + r1) * 512 + o1;
  const bf16* Bk0 = Btk + (size_t)(colBase + r0) * 512 + o0;
  const bf16* Bk1 = Btk + (size_t)(colBase + r1) * 512 + o1;
  const bf16* Bv0 = Btv + (size_t)(colBase + r0) * 512 + o0;
  const bf16* Bv1 = Btv + (size_t)(colBase + r1) * 512 + o1;

  const int wr = (w & 1) * 64;
  const int wc = (w >> 1) * 64;

  for (int kt = 0; kt < 16; ++kt) {
    const int k0 = kt * 32;
    __syncthreads();
    async_lds16(A0 + k0, sA + c0 * 8);
    async_lds16(A1 + k0, sA + c1 * 8);
    async_lds16(Bk0 + k0, sBk + c0 * 8);
    async_lds16(Bk1 + k0, sBk + c1 * 8);
    async_lds16(Bv0 + k0, sBv + c0 * 8);
    async_lds16(Bv1 + k0, sBv + c1 * 8);
    __syncthreads();
    bf16x8 a[4], b[4], bv2[4];
#pragma unroll
    for (int i = 0; i < 4; ++i)
      a[i] = *(const bf16x8*)(sA + (wr + i * 16 + fm) * 32 + fq * 8);
#pragma unroll
    for (int j = 0; j < 4; ++j) {
      b[j] = *(const bf16x8*)(sBk + (wc + j * 16 + fm) * 32 + fq * 8);
      bv2[j] = *(const bf16x8*)(sBv + (wc + j * 16 + fm) * 32 + fq * 8);
    }
#pragma unroll
    for (int i = 0; i < 4; ++i)
#pragma unroll
      for (int j = 0; j < 4; ++j) {
        acck[i][j] = MFMA16(a[i], b[j], acck[i][j]);
        accv[i][j] = MFMA16(a[i], bv2[j], accv[i][j]);
      }
  }

  const int bidx = (int)(rowBase >> 10);
#pragma unroll
  for (int i = 0; i < 4; ++i) {
#pragma unroll
    for (int r = 0; r < 4; ++r) {
      const long R = rowBase + wr + i * 16 + fq * 4 + r;
      const float mk = (float)Km[R];
      bf16* outrow = Kp + R * 512;
#pragma unroll
      for (int j = 0; j < 4; ++j) {
        const int C = colBase + wc + j * 16 + fm;
        outrow[C] = (bf16)((acck[i][j][r] + (float)bk[C]) * mk);
      }
    }
    // V: transposed store, r -> 4 consecutive kk (8B store)
    const int kkb = (int)(rowBase & 1023) + wr + i * 16 + fq * 4;
#pragma unroll
    for (int j = 0; j < 4; ++j) {
      const int C = colBase + wc + j * 16 + fm;
      const float bvc = (float)bv[C];
      bf16x4 pv;
#pragma unroll
      for (int r = 0; r < 4; ++r) pv[r] = (bf16)(accv[i][j][r] + bvc);
      bf16* dst = Vt + ((size_t)(bidx * 8 + (C >> 6)) * 64 + (C & 63)) * 1024 + kkb;
      *(bf16x4*)((void*)dst) = pv;
    }
  }
}

// ---------------------------------------------------------------------------
// Attention: 128-q-row blocks, wave owns 32 q-rows (2 subtiles of 16).
// Grid 1024 linear, XCD-swizzled (id&7==h). S^T MFMA: A=K rows, B=Q rows;
// kf/vf fragments shared across the 2 q-subtiles (halved LDS reads/MFMA).
// y = exp2(exp2(s*c1)*kml); binary Qm factored to epilogue.
// R10: T14 async-stage (K/V/Km reg double-buffer across kt; next-tile
// loads issued post-barrier, latency hidden under compute) + T5 setprio
// around MFMA clusters. LDS 37.6KB, 4 blocks/CU. O in-place over Qp.
// ---------------------------------------------------------------------------
__global__ __launch_bounds__(256, 4) void attn_kernel(
    bf16* __restrict__ Qp, const bf16* __restrict__ Kp,
    const bf16* __restrict__ Vt, const bf16* __restrict__ Qm,
    const bf16* __restrict__ Km) {
  __shared__ bf16 sK[64][72];      // [kk][d]
  __shared__ bf16 sVt[64][72];     // [d][kk]
  __shared__ bf16 sX[4][32][72];   // per-wave [q][kk]
  __shared__ float sKl[64];        // km * log2e
  __shared__ float sL[4][32];

  const int tid = threadIdx.x;
  const int lane = tid & 63;
  const int w = tid >> 6;
  const int fm = lane & 15;
  const int fq = lane >> 4;
  const int id = blockIdx.x;
  const int bh = id & 127;         // id%8 == h -> XCD locality for K/V
  const int q0 = (id >> 7) * 128;
  const int b = bh >> 3;
  const int hh = bh & 7;

  bf16* Qbase = Qp + ((long)b * 1024 + q0) * 512 + hh * 64;
  float qm_lane[2];
  qm_lane[0] = (float)Qm[(long)b * 1024 + q0 + w * 32 + fm];
  qm_lane[1] = (float)Qm[(long)b * 1024 + q0 + w * 32 + 16 + fm];

  // loop-invariant Q fragments straight from global: [subtile u][ks]
  bf16x8 qf[2][2];
#pragma unroll
  for (int u = 0; u < 2; ++u)
#pragma unroll
    for (int ks = 0; ks < 2; ++ks)
      qf[u][ks] = *(const bf16x8*)(Qbase + (long)(w * 32 + u * 16 + fm) * 512 +
                                   ks * 32 + fq * 8);

  f32x4 acc_o[2][4] = {};
  float l_lane[2] = {0.f, 0.f};
  const float c1 = 0.063758715f;   // log2(e)/sqrt(512)
  const float LOG2E = 1.4426950408889634f;

  const bf16* Vthead = Vt + ((long)b * 8 + hh) * 64 * 1024;  // [d][kk]
  const bf16* Kbb = Kp + (long)b * 1024 * 512 + hh * 64;
  const bf16* Kmb = Km + (long)b * 1024;

  // staging register double-buffer: thread covers rows srow0, srow1
  const int srow0 = tid >> 3;            // 0..31
  const int srow1 = srow0 + 32;          // 32..63
  const int scol = (tid & 7) * 8;
  bf16x8 kreg0, kreg1, vreg0, vreg1;
  float klreg = 0.f;
  {
    const bf16* Kbase = Kbb;             // kt = 0
    kreg0 = *(const bf16x8*)(Kbase + (long)srow0 * 512 + scol);
    kreg1 = *(const bf16x8*)(Kbase + (long)srow1 * 512 + scol);
    vreg0 = *(const bf16x8*)(Vthead + (long)srow0 * 1024 + scol);
    vreg1 = *(const bf16x8*)(Vthead + (long)srow1 * 1024 + scol);
    if (tid < 64) klreg = (float)Kmb[tid];
  }

  for (int kt = 0; kt < 16; ++kt) {
    __syncthreads();                     // previous kt's LDS reads done
    *(bf16x8*)(&sK[srow0][scol]) = kreg0;
    *(bf16x8*)(&sK[srow1][scol]) = kreg1;
    *(bf16x8*)(&sVt[srow0][scol]) = vreg0;
    *(bf16x8*)(&sVt[srow1][scol]) = vreg1;
    if (tid < 64) sKl[tid] = klreg * LOG2E;
    __syncthreads();                     // staging visible

    // issue next tile's loads now; latency hides under compute below
    if (kt < 15) {
      const int kk1 = (kt + 1) * 64;
      const bf16* Kn = Kbb + (long)kk1 * 512;
      kreg0 = *(const bf16x8*)(Kn + (long)srow0 * 512 + scol);
      kreg1 = *(const bf16x8*)(Kn + (long)srow1 * 512 + scol);
      vreg0 = *(const bf16x8*)(Vthead + (long)srow0 * 1024 + kk1 + scol);
      vreg1 = *(const bf16x8*)(Vthead + (long)srow1 * 1024 + kk1 + scol);
      if (tid < 64) klreg = (float)Kmb[kk1 + tid];
    }

    // S^T: C[kk 64][q 32]; A = K rows (m=kk), B = Q rows (n=q, 2 subtiles)
    f32x4 s_acc[2][4] = {};
    __builtin_amdgcn_s_setprio(1);
#pragma unroll
    for (int ks = 0; ks < 2; ++ks)
#pragma unroll
      for (int t = 0; t < 4; ++t) {
        const bf16x8 kf = *(const bf16x8*)(&sK[t * 16 + fm][ks * 32 + fq * 8]);
        s_acc[0][t] = MFMA16(kf, qf[0][ks], s_acc[0][t]);
        s_acc[1][t] = MFMA16(kf, qf[1][ks], s_acc[1][t]);
      }
    __builtin_amdgcn_s_setprio(0);
    // lane holds q=fm (subtile u), kk = t*16 + fq*4 + r
#pragma unroll
    for (int u = 0; u < 2; ++u)
#pragma unroll
      for (int t = 0; t < 4; ++t) {
        const f32x4 kml4 = *(const f32x4*)(&sKl[t * 16 + fq * 4]);
        bf16x4 xp;
#pragma unroll
        for (int r = 0; r < 4; ++r) {
          const float e1 = EXP2F(s_acc[u][t][r] * c1);
          const float y = EXP2F(e1 * kml4[r]);
          l_lane[u] += y;
          xp[r] = (bf16)y;
        }
        *(bf16x4*)((void*)&sX[w][u * 16 + fm][t * 16 + fq * 4]) = xp;
      }
    // PV: C[q 32][d 64]; A = sX rows (2 subtiles), B = sVt rows (shared)
    __builtin_amdgcn_s_setprio(1);
#pragma unroll
    for (int ks = 0; ks < 2; ++ks) {
      const bf16x8 xf0 = *(const bf16x8*)(&sX[w][fm][ks * 32 + fq * 8]);
      const bf16x8 xf1 = *(const bf16x8*)(&sX[w][16 + fm][ks * 32 + fq * 8]);
#pragma unroll
      for (int t = 0; t < 4; ++t) {
        const bf16x8 vf = *(const bf16x8*)(&sVt[t * 16 + fm][ks * 32 + fq * 8]);
        acc_o[0][t] = MFMA16(xf0, vf, acc_o[0][t]);
        acc_o[1][t] = MFMA16(xf1, vf, acc_o[1][t]);
      }
    }
    __builtin_amdgcn_s_setprio(0);
  }

  // per-q Y-sums
#pragma unroll
  for (int u = 0; u < 2; ++u) {
    l_lane[u] += __shfl_xor(l_lane[u], 16);
    l_lane[u] += __shfl_xor(l_lane[u], 32);
    if (fq == 0) sL[w][u * 16 + fm] = l_lane[u];
  }
  __syncthreads();

  // epilogue: lane holds q = u*16 + fq*4 + r, d = t*16 + fm (PV C-layout)
  // residual re-read from global; same-thread read-then-write, no hazard.
#pragma unroll
  for (int u = 0; u < 2; ++u) {
#pragma unroll
    for (int t = 0; t < 4; ++t) {
#pragma unroll
      for (int r = 0; r < 4; ++r) {
        const int qr = w * 32 + u * 16 + fq * 4 + r;
        const int dc = t * 16 + fm;
        const float qm_r = __shfl(qm_lane[u], fq * 4 + r, 64);
        const float li = 1.0f / (qm_r * sL[w][u * 16 + fq * 4 + r] + 1e-8f);
        const float val =
            (float)Qbase[(long)qr * 512 + dc] + qm_r * acc_o[u][t][r] * li;
        Qbase[(long)qr * 512 + dc] = (bf16)val;
      }
    }
  }
}

// ---------------------------------------------------------------------------
// LayerNorm (bf16 -> bf16). One wave per row. In-place safe.
// ---------------------------------------------------------------------------
__global__ __launch_bounds__(256) void lnorm(
    const bf16* __restrict__ X, const bf16* __restrict__ g,
    const bf16* __restrict__ bb, bf16* __restrict__ out) {
  const int row = blockIdx.x * 4 + (threadIdx.x >> 6);
  const int lane = threadIdx.x & 63;
  const bf16x8 v = *(const bf16x8*)(X + (size_t)row * 512 + lane * 8);
  float x[8], s = 0.f, ss = 0.f;
#pragma unroll
  for (int j = 0; j < 8; ++j) {
    x[j] = (float)v[j];
    s += x[j];
    ss += x[j] * x[j];
  }
#pragma unroll
  for (int m = 1; m < 64; m <<= 1) {
    s += __shfl_xor(s, m);
    ss += __shfl_xor(ss, m);
  }
  const float mean = s * (1.0f / 512.0f);
  const float var = ss * (1.0f / 512.0f) - mean * mean;
  const float rstd = 1.0f / sqrtf(var + 1e-5f);
  const bf16x8 gv = *(const bf16x8*)(g + lane * 8);
  const bf16x8 bv = *(const bf16x8*)(bb + lane * 8);
  bf16x8 o;
#pragma unroll
  for (int j = 0; j < 8; ++j)
    o[j] = (bf16)((x[j] - mean) * rstd * (float)gv[j] + (float)bv[j]);
  *(bf16x8*)(out + (size_t)row * 512 + lane * 8) = o;
}

// ---------------------------------------------------------------------------
// Final LayerNorm: bf16 in, f32 out.
// ---------------------------------------------------------------------------
__global__ __launch_bounds__(256) void lnorm_out(
    const bf16* __restrict__ X, const bf16* __restrict__ g,
    const bf16* __restrict__ bb, float* __restrict__ out) {
  const int row = blockIdx.x * 4 + (threadIdx.x >> 6);
  const int lane = threadIdx.x & 63;
  const bf16x8 v = *(const bf16x8*)(X + (size_t)row * 512 + lane * 8);
  float x[8], s = 0.f, ss = 0.f;
#pragma unroll
  for (int j = 0; j < 8; ++j) {
    x[j] = (float)v[j];
    s += x[j];
    ss += x[j] * x[j];
  }
#pragma unroll
  for (int m = 1; m < 64; m <<= 1) {
    s += __shfl_xor(s, m);
    ss += __shfl_xor(ss, m);
  }
  const float mean = s * (1.0f / 512.0f);
  const float var = ss * (1.0f / 512.0f) - mean * mean;
  const float rstd = 1.0f / sqrtf(var + 1e-5f);
  const bf16x8 gv = *(const bf16x8*)(g + lane * 8);
  const bf16x8 bv = *(const bf16x8*)(bb + lane * 8);
  f32x4 a, c;
#pragma unroll
  for (int j = 0; j < 4; ++j) {
    a[j] = (x[j] - mean) * rstd * (float)gv[j] + (float)bv[j];
    c[j] = (x[j + 4] - mean) * rstd * (float)gv[j + 4] + (float)bv[j + 4];
  }
  float* fo = out + (size_t)row * 512 + lane * 8;
  *(f32x4*)fo = a;
  *(f32x4*)(fo + 4) = c;
}

// ---------------------------------------------------------------------------
extern "C" void kernel_launch(void* const* d_in, const int* in_sizes, int n_in,
                              void* d_out, int out_size, void* d_ws, size_t ws_size,
                              hipStream_t stream) {
  (void)in_sizes; (void)n_in; (void)out_size; (void)ws_size;
  const float* Q = (const float*)d_in[0];
  const float* K = (const float*)d_in[1];

  bf16* ws = (bf16*)d_ws;
  const long W2 = 512L * 512;
  const long MN = 16384L * 512;
  bf16* Tq = ws;                           // 4 transposed bf16 weights: 2MB
  bf16* Tk = Tq + W2;
  bf16* Tv = Tk + W2;
  bf16* To = Tv + W2;
  bf16* sm = To + W2;                      // 8 x 512 smalls
  bf16* cQm = sm + 8 * 512;                // 16384
  bf16* cKm = cQm + 16384;                 // 16384
  bf16* Qp = cKm + 16384;                  // 16MB
  bf16* Kp = Qp + MN;                      // 16MB; Qbf borrows this pre-gemmKV
  bf16* Qbf = Kp;                          // Q bf16 (dead after Q-gemm)
  bf16* Kbf = (bf16*)d_out;                // K bf16 in d_out lower 16MB
  bf16* Vt = (bf16*)d_out + MN;            // V^T in d_out upper 16MB

  bf16* cbq = sm + 0 * 512;
  bf16* cbk = sm + 1 * 512;
  bf16* cbv = sm + 2 * 512;
  bf16* cbo = sm + 3 * 512;
  bf16* cg0 = sm + 4 * 512;
  bf16* cb0 = sm + 5 * 512;
  bf16* cg1 = sm + 6 * 512;
  bf16* cb1 = sm + 7 * 512;

  transposeW<<<dim3(8, 8, 4), 256, 0, stream>>>(
      (const float*)d_in[4], (const float*)d_in[6],
      (const float*)d_in[8], (const float*)d_in[10], Tq, Tk, Tv, To);

  ConvArgs ca;
  ca.src[0] = (const float*)d_in[2];  ca.dst[0] = cQm; ca.n[0] = 16384;
  ca.src[1] = (const float*)d_in[3];  ca.dst[1] = cKm; ca.n[1] = 16384;
  ca.src[2] = (const float*)d_in[5];  ca.dst[2] = cbq; ca.n[2] = 512;
  ca.src[3] = (const float*)d_in[7];  ca.dst[3] = cbk; ca.n[3] = 512;
  ca.src[4] = (const float*)d_in[9];  ca.dst[4] = cbv; ca.n[4] = 512;
  ca.src[5] = (const float*)d_in[11]; ca.dst[5] = cbo; ca.n[5] = 512;
  ca.src[6] = (const float*)d_in[12]; ca.dst[6] = cg0; ca.n[6] = 512;
  ca.src[7] = (const float*)d_in[13]; ca.dst[7] = cb0; ca.n[7] = 512;
  ca.src[8] = (const float*)d_in[14]; ca.dst[8] = cg1; ca.n[8] = 512;
  ca.src[9] = (const float*)d_in[15]; ca.dst[9] = cb1; ca.n[9] = 512;
  convert_all<<<dim3(8, 1, 10), 256, 0, stream>>>(ca);

  convertX<<<dim3(4096, 2), 256, 0, stream>>>(Q, K, Qbf, Kbf);

  gemm512<<<512, 256, 0, stream>>>(Qbf, Tq, cbq, cQm, nullptr, Qp);
  gemmKV<<<512, 256, 0, stream>>>(Kbf, Tk, Tv, cbk, cbv, cKm, Kp, Vt);

  attn_kernel<<<1024, 256, 0, stream>>>(Qp, Kp, Vt, cQm, cKm);

  lnorm<<<4096, 256, 0, stream>>>(Qp, cg0, cb0, Qp);
  gemm512<<<512, 256, 0, stream>>>(Qp, To, cbo, nullptr, Qp, Kp);
  lnorm_out<<<4096, 256, 0, stream>>>(Kp, cg1, cb1, (float*)d_out);
}

// Round 4
// 296.280 us; speedup vs baseline: 1.0513x; 1.0513x over previous
//
#include <hip/hip_runtime.h>
#include <hip/hip_bf16.h>
#include <cstdint>

// ---------------------------------------------------------------------------
// MAB block (f32 in/out, bf16 internal):
//   Qp=(Q@Wq+bq)*Qm; Kp=(K@Wk+bk)*Km; V=K@Wv+bv
//   S = Qh Kh^T / sqrt(512);  X = exp(exp(S)*Km)*Qm;  A = X/(sum+1e-8)
//   O = Qh + A@Vh;  O = LN0(O);  O = O + relu(O@Wo+bo);  out = LN1(O)
//
// R9:  attn 2->4 blocks/CU (sQ dropped). 81 -> 74 us, Occ 20->33.
// R10: FAILED: reg-staged T14 spilled (unified VGPR+AGPR budget = 128 at
//      4 waves/SIMD was already full; +17 staging VGPRs -> scratch ->
//      WRITE_SIZE 35->89MB, attn 74->95). Reverted.
// R11: (1) attn = R9 + s_setprio(1) around MFMA clusters only (T5, zero
//      register cost). (2) convertX fused into projection GEMMs: A staged
//      via regs with f32->bf16 cvt (B stays async global_load_lds).
//      Removes 133MB of convertX traffic + one dispatch.
// Buffers: ws ~36MB (T, smalls, masks, Qp, Kp); d_out upper 16MB = Vt
// (dead before final LN writes).
// ---------------------------------------------------------------------------

typedef __bf16 bf16;
typedef __bf16 bf16x4 __attribute__((ext_vector_type(4)));
typedef __bf16 bf16x8 __attribute__((ext_vector_type(8)));
typedef float f32x4 __attribute__((ext_vector_type(4)));

#define MFMA16(a, b, c) __builtin_amdgcn_mfma_f32_16x16x32_bf16((a), (b), (c), 0, 0, 0)

#if __has_builtin(__builtin_amdgcn_exp2f)
#define EXP2F(x) __builtin_amdgcn_exp2f(x)
#else
#define EXP2F(x) exp2f(x)
#endif

static __device__ __forceinline__ void async_lds16(const bf16* g, bf16* l) {
  __builtin_amdgcn_global_load_lds(
      (__attribute__((address_space(1))) void*)(void*)g,
      (__attribute__((address_space(3))) void*)l,
      16, 0, 0);
}

// XCD swizzle for 512-block GEMM grids: 4 col-blocks of one row share id&7.
static __device__ __forceinline__ void swz512(int id, long& rowBase, int& colBase) {
  colBase = ((id >> 3) & 3) * 128;
  rowBase = (long)((id & 7) + 8 * (id >> 5)) * 128;
}

// ---------------------------------------------------------------------------
// Weight convert+transpose: T[n][k] = (bf16)W[k][n], 512x512, f32 in.
// ---------------------------------------------------------------------------
__global__ __launch_bounds__(256) void transposeW(
    const float* __restrict__ Wq, const float* __restrict__ Wk,
    const float* __restrict__ Wv, const float* __restrict__ Wo,
    bf16* __restrict__ Tq, bf16* __restrict__ Tk,
    bf16* __restrict__ Tv, bf16* __restrict__ To) {
  const float* src;
  bf16* dst;
  switch (blockIdx.z) {
    case 0: src = Wq; dst = Tq; break;
    case 1: src = Wk; dst = Tk; break;
    case 2: src = Wv; dst = Tv; break;
    default: src = Wo; dst = To; break;
  }
  __shared__ bf16 t[64][72];
  const int tid = threadIdx.x;
  const int n0 = blockIdx.x * 64;
  const int k0 = blockIdx.y * 64;
  for (int c = tid; c < 512; c += 256) {
    const int row = c >> 3, col = (c & 7) * 8;   // row: k, col: n
    const float* sp = src + (size_t)(k0 + row) * 512 + n0 + col;
    const f32x4 a = *(const f32x4*)sp;
    const f32x4 b = *(const f32x4*)(sp + 4);
    bf16x8 v;
#pragma unroll
    for (int j = 0; j < 4; ++j) { v[j] = (bf16)a[j]; v[j + 4] = (bf16)b[j]; }
    *(bf16x8*)(&t[row][col]) = v;
  }
  __syncthreads();
  for (int c = tid; c < 512; c += 256) {
    const int row = c >> 3, col8 = (c & 7) * 8;  // row: n, col8: k
    bf16x8 v;
#pragma unroll
    for (int j = 0; j < 8; ++j) v[j] = t[col8 + j][row];
    *(bf16x8*)(dst + (size_t)(n0 + row) * 512 + k0 + col8) = v;
  }
}

// ---------------------------------------------------------------------------
// Batched f32->bf16 conversion of 10 small arrays.
// ---------------------------------------------------------------------------
struct ConvArgs {
  const float* src[10];
  bf16* dst[10];
  int n[10];
};

__global__ __launch_bounds__(256) void convert_all(ConvArgs a) {
  const int seg = blockIdx.z;
  const int n = a.n[seg];
  const long i = ((long)blockIdx.x * 256 + threadIdx.x) * 8;
  if (i >= n) return;
  const float* s = a.src[seg];
  const f32x4 x0 = *(const f32x4*)(s + i);
  const f32x4 x1 = *(const f32x4*)(s + i + 4);
  bf16x8 o;
#pragma unroll
  for (int j = 0; j < 4; ++j) { o[j] = (bf16)x0[j]; o[j + 4] = (bf16)x1[j]; }
  *(bf16x8*)(a.dst[seg] + i) = o;
}

// ---------------------------------------------------------------------------
// GEMM (bf16 A): out[M x 512] = epilogue(A @ Bt^T + bias).
//   mask != null : out = (acc+bias) * mask[row]
//   resid != null: out = resid + relu(acc+bias)
// m97 structure; XCD-swizzled linear grid (512 blocks).
// ---------------------------------------------------------------------------
__global__ __launch_bounds__(256, 2) void gemm512(
    const bf16* __restrict__ A, const bf16* __restrict__ Bt,
    const bf16* __restrict__ bias, const bf16* __restrict__ mask,
    const bf16* __restrict__ resid, bf16* __restrict__ out) {
  __shared__ bf16 sA[128 * 32];
  __shared__ bf16 sB[128 * 32];
  const int tid = threadIdx.x;
  const int lane = tid & 63;
  const int w = tid >> 6;
  const int fm = lane & 15;
  const int fq = lane >> 4;
  long rowBase; int colBase;
  swz512(blockIdx.x, rowBase, colBase);

  f32x4 acc[4][4] = {};

  const int c0 = tid, c1 = tid + 256;
  const int r0 = c0 >> 2, o0 = (c0 & 3) * 8;
  const int r1 = c1 >> 2, o1 = (c1 & 3) * 8;
  const bf16* A0 = A + (rowBase + r0) * 512 + o0;
  const bf16* A1 = A + (rowBase + r1) * 512 + o1;
  const bf16* B0 = Bt + (size_t)(colBase + r0) * 512 + o0;
  const bf16* B1 = Bt + (size_t)(colBase + r1) * 512 + o1;

  const int wr = (w & 1) * 64;
  const int wc = (w >> 1) * 64;

  for (int kt = 0; kt < 16; ++kt) {
    const int k0 = kt * 32;
    __syncthreads();
    async_lds16(A0 + k0, sA + c0 * 8);
    async_lds16(A1 + k0, sA + c1 * 8);
    async_lds16(B0 + k0, sB + c0 * 8);
    async_lds16(B1 + k0, sB + c1 * 8);
    __syncthreads();
    bf16x8 a[4], b[4];
#pragma unroll
    for (int i = 0; i < 4; ++i)
      a[i] = *(const bf16x8*)(sA + (wr + i * 16 + fm) * 32 + fq * 8);
#pragma unroll
    for (int j = 0; j < 4; ++j)
      b[j] = *(const bf16x8*)(sB + (wc + j * 16 + fm) * 32 + fq * 8);
#pragma unroll
    for (int i = 0; i < 4; ++i)
#pragma unroll
      for (int j = 0; j < 4; ++j)
        acc[i][j] = MFMA16(a[i], b[j], acc[i][j]);
  }

  // epilogue; C/D layout: col = lane&15, row = (lane>>4)*4 + r
#pragma unroll
  for (int i = 0; i < 4; ++i) {
#pragma unroll
    for (int r = 0; r < 4; ++r) {
      const long R = rowBase + wr + i * 16 + fq * 4 + r;
      const float mk = mask ? (float)mask[R] : 1.0f;
      const bf16* resrow = resid ? resid + R * 512 : nullptr;
      bf16* outrow = out + R * 512;
#pragma unroll
      for (int j = 0; j < 4; ++j) {
        const int C = colBase + wc + j * 16 + fm;
        float v = acc[i][j][r] + (float)bias[C];
        if (mask) v *= mk;
        if (resid) v = (float)resrow[C] + fmaxf(v, 0.0f);
        outrow[C] = (bf16)v;
      }
    }
  }
}

// ---------------------------------------------------------------------------
// R11: Q projection with fused f32->bf16 A conversion.
// A is f32 [M x 512]; staged via regs (f32x4 x2 -> cvt -> ds_write_b128).
// out = (A@Bt^T + bias) * mask[row].
// ---------------------------------------------------------------------------
__global__ __launch_bounds__(256, 2) void gemm512_f32A(
    const float* __restrict__ A, const bf16* __restrict__ Bt,
    const bf16* __restrict__ bias, const bf16* __restrict__ mask,
    bf16* __restrict__ out) {
  __shared__ bf16 sA[128 * 32];
  __shared__ bf16 sB[128 * 32];
  const int tid = threadIdx.x;
  const int lane = tid & 63;
  const int w = tid >> 6;
  const int fm = lane & 15;
  const int fq = lane >> 4;
  long rowBase; int colBase;
  swz512(blockIdx.x, rowBase, colBase);

  f32x4 acc[4][4] = {};

  const int c0 = tid, c1 = tid + 256;
  const int r0 = c0 >> 2, o0 = (c0 & 3) * 8;
  const int r1 = c1 >> 2, o1 = (c1 & 3) * 8;
  const float* A0 = A + (rowBase + r0) * 512 + o0;
  const float* A1 = A + (rowBase + r1) * 512 + o1;
  const bf16* B0 = Bt + (size_t)(colBase + r0) * 512 + o0;
  const bf16* B1 = Bt + (size_t)(colBase + r1) * 512 + o1;

  const int wr = (w & 1) * 64;
  const int wc = (w >> 1) * 64;

  for (int kt = 0; kt < 16; ++kt) {
    const int k0 = kt * 32;
    __syncthreads();
    // B: async direct-to-LDS; A: reg-staged with cvt (issued after so the
    // DMA runs while we convert).
    async_lds16(B0 + k0, sB + c0 * 8);
    async_lds16(B1 + k0, sB + c1 * 8);
    {
      const f32x4 x0 = *(const f32x4*)(A0 + k0);
      const f32x4 x1 = *(const f32x4*)(A0 + k0 + 4);
      const f32x4 y0 = *(const f32x4*)(A1 + k0);
      const f32x4 y1 = *(const f32x4*)(A1 + k0 + 4);
      bf16x8 va, vb;
#pragma unroll
      for (int j = 0; j < 4; ++j) {
        va[j] = (bf16)x0[j]; va[j + 4] = (bf16)x1[j];
        vb[j] = (bf16)y0[j]; vb[j + 4] = (bf16)y1[j];
      }
      *(bf16x8*)(sA + c0 * 8) = va;
      *(bf16x8*)(sA + c1 * 8) = vb;
    }
    __syncthreads();
    bf16x8 a[4], b[4];
#pragma unroll
    for (int i = 0; i < 4; ++i)
      a[i] = *(const bf16x8*)(sA + (wr + i * 16 + fm) * 32 + fq * 8);
#pragma unroll
    for (int j = 0; j < 4; ++j)
      b[j] = *(const bf16x8*)(sB + (wc + j * 16 + fm) * 32 + fq * 8);
#pragma unroll
    for (int i = 0; i < 4; ++i)
#pragma unroll
      for (int j = 0; j < 4; ++j)
        acc[i][j] = MFMA16(a[i], b[j], acc[i][j]);
  }

#pragma unroll
  for (int i = 0; i < 4; ++i) {
#pragma unroll
    for (int r = 0; r < 4; ++r) {
      const long R = rowBase + wr + i * 16 + fq * 4 + r;
      const float mk = (float)mask[R];
      bf16* outrow = out + R * 512;
#pragma unroll
      for (int j = 0; j < 4; ++j) {
        const int C = colBase + wc + j * 16 + fm;
        outrow[C] = (bf16)((acc[i][j][r] + (float)bias[C]) * mk);
      }
    }
  }
}

// ---------------------------------------------------------------------------
// Fused K/V projection, f32 A with fused conversion (R11).
//   Kp[R][C] = (A@Tk^T + bk) * Km[R];  Vt[...] transposed V store.
// ---------------------------------------------------------------------------
__global__ __launch_bounds__(256, 2) void gemmKV_f32A(
    const float* __restrict__ A, const bf16* __restrict__ Btk,
    const bf16* __restrict__ Btv, const bf16* __restrict__ bk,
    const bf16* __restrict__ bv, const bf16* __restrict__ Km,
    bf16* __restrict__ Kp, bf16* __restrict__ Vt) {
  __shared__ bf16 sA[128 * 32];
  __shared__ bf16 sBk[128 * 32];
  __shared__ bf16 sBv[128 * 32];
  const int tid = threadIdx.x;
  const int lane = tid & 63;
  const int w = tid >> 6;
  const int fm = lane & 15;
  const int fq = lane >> 4;
  long rowBase; int colBase;
  swz512(blockIdx.x, rowBase, colBase);

  f32x4 acck[4][4] = {};
  f32x4 accv[4][4] = {};

  const int c0 = tid, c1 = tid + 256;
  const int r0 = c0 >> 2, o0 = (c0 & 3) * 8;
  const int r1 = c1 >> 2, o1 = (c1 & 3) * 8;
  const float* A0 = A + (rowBase + r0) * 512 + o0;
  const float* A1 = A + (rowBase + r1) * 512 + o1;
  const bf16* Bk0 = Btk + (size_t)(colBase + r0) * 512 + o0;
  const bf16* Bk1 = Btk + (size_t)(colBase + r1) * 512 + o1;
  const bf16* Bv0 = Btv + (size_t)(colBase + r0) * 512 + o0;
  const bf16* Bv1 = Btv + (size_t)(colBase + r1) * 512 + o1;

  const int wr = (w & 1) * 64;
  const int wc = (w >> 1) * 64;

  for (int kt = 0; kt < 16; ++kt) {
    const int k0 = kt * 32;
    __syncthreads();
    async_lds16(Bk0 + k0, sBk + c0 * 8);
    async_lds16(Bk1 + k0, sBk + c1 * 8);
    async_lds16(Bv0 + k0, sBv + c0 * 8);
    async_lds16(Bv1 + k0, sBv + c1 * 8);
    {
      const f32x4 x0 = *(const f32x4*)(A0 + k0);
      const f32x4 x1 = *(const f32x4*)(A0 + k0 + 4);
      const f32x4 y0 = *(const f32x4*)(A1 + k0);
      const f32x4 y1 = *(const f32x4*)(A1 + k0 + 4);
      bf16x8 va, vb;
#pragma unroll
      for (int j = 0; j < 4; ++j) {
        va[j] = (bf16)x0[j]; va[j + 4] = (bf16)x1[j];
        vb[j] = (bf16)y0[j]; vb[j + 4] = (bf16)y1[j];
      }
      *(bf16x8*)(sA + c0 * 8) = va;
      *(bf16x8*)(sA + c1 * 8) = vb;
    }
    __syncthreads();
    bf16x8 a[4], b[4], bv2[4];
#pragma unroll
    for (int i = 0; i < 4; ++i)
      a[i] = *(const bf16x8*)(sA + (wr + i * 16 + fm) * 32 + fq * 8);
#pragma unroll
    for (int j = 0; j < 4; ++j) {
      b[j] = *(const bf16x8*)(sBk + (wc + j * 16 + fm) * 32 + fq * 8);
      bv2[j] = *(const bf16x8*)(sBv + (wc + j * 16 + fm) * 32 + fq * 8);
    }
#pragma unroll
    for (int i = 0; i < 4; ++i)
#pragma unroll
      for (int j = 0; j < 4; ++j) {
        acck[i][j] = MFMA16(a[i], b[j], acck[i][j]);
        accv[i][j] = MFMA16(a[i], bv2[j], accv[i][j]);
      }
  }

  const int bidx = (int)(rowBase >> 10);
#pragma unroll
  for (int i = 0; i < 4; ++i) {
#pragma unroll
    for (int r = 0; r < 4; ++r) {
      const long R = rowBase + wr + i * 16 + fq * 4 + r;
      const float mk = (float)Km[R];
      bf16* outrow = Kp + R * 512;
#pragma unroll
      for (int j = 0; j < 4; ++j) {
        const int C = colBase + wc + j * 16 + fm;
        outrow[C] = (bf16)((acck[i][j][r] + (float)bk[C]) * mk);
      }
    }
    // V: transposed store, r -> 4 consecutive kk (8B store)
    const int kkb = (int)(rowBase & 1023) + wr + i * 16 + fq * 4;
#pragma unroll
    for (int j = 0; j < 4; ++j) {
      const int C = colBase + wc + j * 16 + fm;
      const float bvc = (float)bv[C];
      bf16x4 pv;
#pragma unroll
      for (int r = 0; r < 4; ++r) pv[r] = (bf16)(accv[i][j][r] + bvc);
      bf16* dst = Vt + ((size_t)(bidx * 8 + (C >> 6)) * 64 + (C & 63)) * 1024 + kkb;
      *(bf16x4*)((void*)dst) = pv;
    }
  }
}

// ---------------------------------------------------------------------------
// Attention: 128-q-row blocks, wave owns 32 q-rows (2 subtiles of 16).
// Grid 1024 linear, XCD-swizzled (id&7==h). S^T MFMA: A=K rows, B=Q rows;
// kf/vf fragments shared across the 2 q-subtiles (halved LDS reads/MFMA).
// y = exp2(exp2(s*c1)*kml); binary Qm factored to epilogue.
// R11 = R9 structure (direct LDS staging, no reg double-buffer) + T5
// setprio around MFMA clusters. LDS 37.6KB, 4 blocks/CU. O in-place.
// ---------------------------------------------------------------------------
__global__ __launch_bounds__(256, 4) void attn_kernel(
    bf16* __restrict__ Qp, const bf16* __restrict__ Kp,
    const bf16* __restrict__ Vt, const bf16* __restrict__ Qm,
    const bf16* __restrict__ Km) {
  __shared__ bf16 sK[64][72];      // [kk][d]
  __shared__ bf16 sVt[64][72];     // [d][kk]
  __shared__ bf16 sX[4][32][72];   // per-wave [q][kk]
  __shared__ float sKl[64];        // km * log2e
  __shared__ float sL[4][32];

  const int tid = threadIdx.x;
  const int lane = tid & 63;
  const int w = tid >> 6;
  const int fm = lane & 15;
  const int fq = lane >> 4;
  const int id = blockIdx.x;
  const int bh = id & 127;         // id%8 == h -> XCD locality for K/V
  const int q0 = (id >> 7) * 128;
  const int b = bh >> 3;
  const int hh = bh & 7;

  bf16* Qbase = Qp + ((long)b * 1024 + q0) * 512 + hh * 64;
  float qm_lane[2];
  qm_lane[0] = (float)Qm[(long)b * 1024 + q0 + w * 32 + fm];
  qm_lane[1] = (float)Qm[(long)b * 1024 + q0 + w * 32 + 16 + fm];

  // loop-invariant Q fragments straight from global: [subtile u][ks]
  bf16x8 qf[2][2];
#pragma unroll
  for (int u = 0; u < 2; ++u)
#pragma unroll
    for (int ks = 0; ks < 2; ++ks)
      qf[u][ks] = *(const bf16x8*)(Qbase + (long)(w * 32 + u * 16 + fm) * 512 +
                                   ks * 32 + fq * 8);

  f32x4 acc_o[2][4] = {};
  float l_lane[2] = {0.f, 0.f};
  const float c1 = 0.063758715f;   // log2(e)/sqrt(512)
  const float LOG2E = 1.4426950408889634f;

  const bf16* Vthead = Vt + ((long)b * 8 + hh) * 64 * 1024;  // [d][kk]
  const bf16* Kbb = Kp + (long)b * 1024 * 512 + hh * 64;
  const bf16* Kmb = Km + (long)b * 1024;

  for (int kt = 0; kt < 16; ++kt) {
    const int kk0 = kt * 64;
    __syncthreads();
    const bf16* Kbase = Kbb + (long)kk0 * 512;
    for (int c = tid; c < 512; c += 256) {
      const int row = c >> 3, col = (c & 7) * 8;
      *(bf16x8*)(&sK[row][col]) = *(const bf16x8*)(Kbase + (long)row * 512 + col);
      *(bf16x8*)(&sVt[row][col]) =
          *(const bf16x8*)(Vthead + (long)row * 1024 + kk0 + col);
    }
    if (tid < 64) sKl[tid] = (float)Kmb[kk0 + tid] * LOG2E;
    __syncthreads();

    // S^T: C[kk 64][q 32]; A = K rows (m=kk), B = Q rows (n=q, 2 subtiles)
    f32x4 s_acc[2][4] = {};
    __builtin_amdgcn_s_setprio(1);
#pragma unroll
    for (int ks = 0; ks < 2; ++ks)
#pragma unroll
      for (int t = 0; t < 4; ++t) {
        const bf16x8 kf = *(const bf16x8*)(&sK[t * 16 + fm][ks * 32 + fq * 8]);
        s_acc[0][t] = MFMA16(kf, qf[0][ks], s_acc[0][t]);
        s_acc[1][t] = MFMA16(kf, qf[1][ks], s_acc[1][t]);
      }
    __builtin_amdgcn_s_setprio(0);
    // lane holds q=fm (subtile u), kk = t*16 + fq*4 + r
#pragma unroll
    for (int u = 0; u < 2; ++u)
#pragma unroll
      for (int t = 0; t < 4; ++t) {
        const f32x4 kml4 = *(const f32x4*)(&sKl[t * 16 + fq * 4]);
        bf16x4 xp;
#pragma unroll
        for (int r = 0; r < 4; ++r) {
          const float e1 = EXP2F(s_acc[u][t][r] * c1);
          const float y = EXP2F(e1 * kml4[r]);
          l_lane[u] += y;
          xp[r] = (bf16)y;
        }
        *(bf16x4*)((void*)&sX[w][u * 16 + fm][t * 16 + fq * 4]) = xp;
      }
    // PV: C[q 32][d 64]; A = sX rows (2 subtiles), B = sVt rows (shared)
    __builtin_amdgcn_s_setprio(1);
#pragma unroll
    for (int ks = 0; ks < 2; ++ks) {
      const bf16x8 xf0 = *(const bf16x8*)(&sX[w][fm][ks * 32 + fq * 8]);
      const bf16x8 xf1 = *(const bf16x8*)(&sX[w][16 + fm][ks * 32 + fq * 8]);
#pragma unroll
      for (int t = 0; t < 4; ++t) {
        const bf16x8 vf = *(const bf16x8*)(&sVt[t * 16 + fm][ks * 32 + fq * 8]);
        acc_o[0][t] = MFMA16(xf0, vf, acc_o[0][t]);
        acc_o[1][t] = MFMA16(xf1, vf, acc_o[1][t]);
      }
    }
    __builtin_amdgcn_s_setprio(0);
  }

  // per-q Y-sums
#pragma unroll
  for (int u = 0; u < 2; ++u) {
    l_lane[u] += __shfl_xor(l_lane[u], 16);
    l_lane[u] += __shfl_xor(l_lane[u], 32);
    if (fq == 0) sL[w][u * 16 + fm] = l_lane[u];
  }
  __syncthreads();

  // epilogue: lane holds q = u*16 + fq*4 + r, d = t*16 + fm (PV C-layout)
  // residual re-read from global; same-thread read-then-write, no hazard.
#pragma unroll
  for (int u = 0; u < 2; ++u) {
#pragma unroll
    for (int t = 0; t < 4; ++t) {
#pragma unroll
      for (int r = 0; r < 4; ++r) {
        const int qr = w * 32 + u * 16 + fq * 4 + r;
        const int dc = t * 16 + fm;
        const float qm_r = __shfl(qm_lane[u], fq * 4 + r, 64);
        const float li = 1.0f / (qm_r * sL[w][u * 16 + fq * 4 + r] + 1e-8f);
        const float val =
            (float)Qbase[(long)qr * 512 + dc] + qm_r * acc_o[u][t][r] * li;
        Qbase[(long)qr * 512 + dc] = (bf16)val;
      }
    }
  }
}

// ---------------------------------------------------------------------------
// LayerNorm (bf16 -> bf16). One wave per row. In-place safe.
// ---------------------------------------------------------------------------
__global__ __launch_bounds__(256) void lnorm(
    const bf16* __restrict__ X, const bf16* __restrict__ g,
    const bf16* __restrict__ bb, bf16* __restrict__ out) {
  const int row = blockIdx.x * 4 + (threadIdx.x >> 6);
  const int lane = threadIdx.x & 63;
  const bf16x8 v = *(const bf16x8*)(X + (size_t)row * 512 + lane * 8);
  float x[8], s = 0.f, ss = 0.f;
#pragma unroll
  for (int j = 0; j < 8; ++j) {
    x[j] = (float)v[j];
    s += x[j];
    ss += x[j] * x[j];
  }
#pragma unroll
  for (int m = 1; m < 64; m <<= 1) {
    s += __shfl_xor(s, m);
    ss += __shfl_xor(ss, m);
  }
  const float mean = s * (1.0f / 512.0f);
  const float var = ss * (1.0f / 512.0f) - mean * mean;
  const float rstd = 1.0f / sqrtf(var + 1e-5f);
  const bf16x8 gv = *(const bf16x8*)(g + lane * 8);
  const bf16x8 bv = *(const bf16x8*)(bb + lane * 8);
  bf16x8 o;
#pragma unroll
  for (int j = 0; j < 8; ++j)
    o[j] = (bf16)((x[j] - mean) * rstd * (float)gv[j] + (float)bv[j]);
  *(bf16x8*)(out + (size_t)row * 512 + lane * 8) = o;
}

// ---------------------------------------------------------------------------
// Final LayerNorm: bf16 in, f32 out.
// ---------------------------------------------------------------------------
__global__ __launch_bounds__(256) void lnorm_out(
    const bf16* __restrict__ X, const bf16* __restrict__ g,
    const bf16* __restrict__ bb, float* __restrict__ out) {
  const int row = blockIdx.x * 4 + (threadIdx.x >> 6);
  const int lane = threadIdx.x & 63;
  const bf16x8 v = *(const bf16x8*)(X + (size_t)row * 512 + lane * 8);
  float x[8], s = 0.f, ss = 0.f;
#pragma unroll
  for (int j = 0; j < 8; ++j) {
    x[j] = (float)v[j];
    s += x[j];
    ss += x[j] * x[j];
  }
#pragma unroll
  for (int m = 1; m < 64; m <<= 1) {
    s += __shfl_xor(s, m);
    ss += __shfl_xor(ss, m);
  }
  const float mean = s * (1.0f / 512.0f);
  const float var = ss * (1.0f / 512.0f) - mean * mean;
  const float rstd = 1.0f / sqrtf(var + 1e-5f);
  const bf16x8 gv = *(const bf16x8*)(g + lane * 8);
  const bf16x8 bv = *(const bf16x8*)(bb + lane * 8);
  f32x4 a, c;
#pragma unroll
  for (int j = 0; j < 4; ++j) {
    a[j] = (x[j] - mean) * rstd * (float)gv[j] + (float)bv[j];
    c[j] = (x[j + 4] - mean) * rstd * (float)gv[j + 4] + (float)bv[j + 4];
  }
  float* fo = out + (size_t)row * 512 + lane * 8;
  *(f32x4*)fo = a;
  *(f32x4*)(fo + 4) = c;
}

// ---------------------------------------------------------------------------
extern "C" void kernel_launch(void* const* d_in, const int* in_sizes, int n_in,
                              void* d_out, int out_size, void* d_ws, size_t ws_size,
                              hipStream_t stream) {
  (void)in_sizes; (void)n_in; (void)out_size; (void)ws_size;
  const float* Q = (const float*)d_in[0];
  const float* K = (const float*)d_in[1];

  bf16* ws = (bf16*)d_ws;
  const long W2 = 512L * 512;
  const long MN = 16384L * 512;
  bf16* Tq = ws;                           // 4 transposed bf16 weights: 2MB
  bf16* Tk = Tq + W2;
  bf16* Tv = Tk + W2;
  bf16* To = Tv + W2;
  bf16* sm = To + W2;                      // 8 x 512 smalls
  bf16* cQm = sm + 8 * 512;                // 16384
  bf16* cKm = cQm + 16384;                 // 16384
  bf16* Qp = cKm + 16384;                  // 16MB
  bf16* Kp = Qp + MN;                      // 16MB
  bf16* Vt = (bf16*)d_out + MN;            // V^T in d_out upper 16MB

  bf16* cbq = sm + 0 * 512;
  bf16* cbk = sm + 1 * 512;
  bf16* cbv = sm + 2 * 512;
  bf16* cbo = sm + 3 * 512;
  bf16* cg0 = sm + 4 * 512;
  bf16* cb0 = sm + 5 * 512;
  bf16* cg1 = sm + 6 * 512;
  bf16* cb1 = sm + 7 * 512;

  transposeW<<<dim3(8, 8, 4), 256, 0, stream>>>(
      (const float*)d_in[4], (const float*)d_in[6],
      (const float*)d_in[8], (const float*)d_in[10], Tq, Tk, Tv, To);

  ConvArgs ca;
  ca.src[0] = (const float*)d_in[2];  ca.dst[0] = cQm; ca.n[0] = 16384;
  ca.src[1] = (const float*)d_in[3];  ca.dst[1] = cKm; ca.n[1] = 16384;
  ca.src[2] = (const float*)d_in[5];  ca.dst[2] = cbq; ca.n[2] = 512;
  ca.src[3] = (const float*)d_in[7];  ca.dst[3] = cbk; ca.n[3] = 512;
  ca.src[4] = (const float*)d_in[9];  ca.dst[4] = cbv; ca.n[4] = 512;
  ca.src[5] = (const float*)d_in[11]; ca.dst[5] = cbo; ca.n[5] = 512;
  ca.src[6] = (const float*)d_in[12]; ca.dst[6] = cg0; ca.n[6] = 512;
  ca.src[7] = (const float*)d_in[13]; ca.dst[7] = cb0; ca.n[7] = 512;
  ca.src[8] = (const float*)d_in[14]; ca.dst[8] = cg1; ca.n[8] = 512;
  ca.src[9] = (const float*)d_in[15]; ca.dst[9] = cb1; ca.n[9] = 512;
  convert_all<<<dim3(8, 1, 10), 256, 0, stream>>>(ca);

  gemm512_f32A<<<512, 256, 0, stream>>>(Q, Tq, cbq, cQm, Qp);
  gemmKV_f32A<<<512, 256, 0, stream>>>(K, Tk, Tv, cbk, cbv, cKm, Kp, Vt);

  attn_kernel<<<1024, 256, 0, stream>>>(Qp, Kp, Vt, cQm, cKm);

  lnorm<<<4096, 256, 0, stream>>>(Qp, cg0, cb0, Qp);
  gemm512<<<512, 256, 0, stream>>>(Qp, To, cbo, nullptr, Qp, Kp);
  lnorm_out<<<4096, 256, 0, stream>>>(Kp, cg1, cb1, (float*)d_out);
}

// Round 5
// 291.194 us; speedup vs baseline: 1.0696x; 1.0175x over previous
//
#include <hip/hip_runtime.h>
#include <hip/hip_bf16.h>
#include <cstdint>

// ---------------------------------------------------------------------------
// MAB block (f32 in/out, bf16 internal):
//   Qp=(Q@Wq+bq)*Qm; Kp=(K@Wk+bk)*Km; V=K@Wv+bv
//   S = Qh Kh^T / sqrt(512);  X = exp(exp(S)*Km)*Qm;  A = X/(sum+1e-8)
//   O = Qh + A@Vh;  O = LN0(O);  O = O + relu(O@Wo+bo);  out = LN1(O)
//
// R9:  attn 2->4 blocks/CU (sQ dropped). 81 -> 74 us, Occ 20->33.
// R10: FAILED: reg-staged T14 in attn spilled (unified VGPR+AGPR = 128 at
//      4 waves/SIMD already full) -> WRITE_SIZE 35->89MB, attn 74->95.
// R11: setprio in attn HURT (lockstep waves, m190 regime): 74->78. f32A
//      fusion neutral: A-load latency exposed between staging barriers.
// R12: (1) attn = exact R9 (no setprio). (2) f32A GEMMs: T14 issue-early/
//      write-late -- A-loads for kt+1 issued AFTER the compute barrier so
//      latency overlaps MFMA; regs cvt+written to LDS next iter. (256,2)
//      budget 256 regs -> +16 VGPR safe.
// Buffers: ws ~36MB (T, smalls, masks, Qp, Kp); d_out upper 16MB = Vt
// (dead before final LN writes).
// ---------------------------------------------------------------------------

typedef __bf16 bf16;
typedef __bf16 bf16x4 __attribute__((ext_vector_type(4)));
typedef __bf16 bf16x8 __attribute__((ext_vector_type(8)));
typedef float f32x4 __attribute__((ext_vector_type(4)));

#define MFMA16(a, b, c) __builtin_amdgcn_mfma_f32_16x16x32_bf16((a), (b), (c), 0, 0, 0)

#if __has_builtin(__builtin_amdgcn_exp2f)
#define EXP2F(x) __builtin_amdgcn_exp2f(x)
#else
#define EXP2F(x) exp2f(x)
#endif

static __device__ __forceinline__ void async_lds16(const bf16* g, bf16* l) {
  __builtin_amdgcn_global_load_lds(
      (__attribute__((address_space(1))) void*)(void*)g,
      (__attribute__((address_space(3))) void*)l,
      16, 0, 0);
}

// XCD swizzle for 512-block GEMM grids: 4 col-blocks of one row share id&7.
static __device__ __forceinline__ void swz512(int id, long& rowBase, int& colBase) {
  colBase = ((id >> 3) & 3) * 128;
  rowBase = (long)((id & 7) + 8 * (id >> 5)) * 128;
}

// ---------------------------------------------------------------------------
// Weight convert+transpose: T[n][k] = (bf16)W[k][n], 512x512, f32 in.
// ---------------------------------------------------------------------------
__global__ __launch_bounds__(256) void transposeW(
    const float* __restrict__ Wq, const float* __restrict__ Wk,
    const float* __restrict__ Wv, const float* __restrict__ Wo,
    bf16* __restrict__ Tq, bf16* __restrict__ Tk,
    bf16* __restrict__ Tv, bf16* __restrict__ To) {
  const float* src;
  bf16* dst;
  switch (blockIdx.z) {
    case 0: src = Wq; dst = Tq; break;
    case 1: src = Wk; dst = Tk; break;
    case 2: src = Wv; dst = Tv; break;
    default: src = Wo; dst = To; break;
  }
  __shared__ bf16 t[64][72];
  const int tid = threadIdx.x;
  const int n0 = blockIdx.x * 64;
  const int k0 = blockIdx.y * 64;
  for (int c = tid; c < 512; c += 256) {
    const int row = c >> 3, col = (c & 7) * 8;   // row: k, col: n
    const float* sp = src + (size_t)(k0 + row) * 512 + n0 + col;
    const f32x4 a = *(const f32x4*)sp;
    const f32x4 b = *(const f32x4*)(sp + 4);
    bf16x8 v;
#pragma unroll
    for (int j = 0; j < 4; ++j) { v[j] = (bf16)a[j]; v[j + 4] = (bf16)b[j]; }
    *(bf16x8*)(&t[row][col]) = v;
  }
  __syncthreads();
  for (int c = tid; c < 512; c += 256) {
    const int row = c >> 3, col8 = (c & 7) * 8;  // row: n, col8: k
    bf16x8 v;
#pragma unroll
    for (int j = 0; j < 8; ++j) v[j] = t[col8 + j][row];
    *(bf16x8*)(dst + (size_t)(n0 + row) * 512 + k0 + col8) = v;
  }
}

// ---------------------------------------------------------------------------
// Batched f32->bf16 conversion of 10 small arrays.
// ---------------------------------------------------------------------------
struct ConvArgs {
  const float* src[10];
  bf16* dst[10];
  int n[10];
};

__global__ __launch_bounds__(256) void convert_all(ConvArgs a) {
  const int seg = blockIdx.z;
  const int n = a.n[seg];
  const long i = ((long)blockIdx.x * 256 + threadIdx.x) * 8;
  if (i >= n) return;
  const float* s = a.src[seg];
  const f32x4 x0 = *(const f32x4*)(s + i);
  const f32x4 x1 = *(const f32x4*)(s + i + 4);
  bf16x8 o;
#pragma unroll
  for (int j = 0; j < 4; ++j) { o[j] = (bf16)x0[j]; o[j + 4] = (bf16)x1[j]; }
  *(bf16x8*)(a.dst[seg] + i) = o;
}

// ---------------------------------------------------------------------------
// GEMM (bf16 A): out[M x 512] = epilogue(A @ Bt^T + bias).
//   mask != null : out = (acc+bias) * mask[row]
//   resid != null: out = resid + relu(acc+bias)
// m97 structure; XCD-swizzled linear grid (512 blocks).
// ---------------------------------------------------------------------------
__global__ __launch_bounds__(256, 2) void gemm512(
    const bf16* __restrict__ A, const bf16* __restrict__ Bt,
    const bf16* __restrict__ bias, const bf16* __restrict__ mask,
    const bf16* __restrict__ resid, bf16* __restrict__ out) {
  __shared__ bf16 sA[128 * 32];
  __shared__ bf16 sB[128 * 32];
  const int tid = threadIdx.x;
  const int lane = tid & 63;
  const int w = tid >> 6;
  const int fm = lane & 15;
  const int fq = lane >> 4;
  long rowBase; int colBase;
  swz512(blockIdx.x, rowBase, colBase);

  f32x4 acc[4][4] = {};

  const int c0 = tid, c1 = tid + 256;
  const int r0 = c0 >> 2, o0 = (c0 & 3) * 8;
  const int r1 = c1 >> 2, o1 = (c1 & 3) * 8;
  const bf16* A0 = A + (rowBase + r0) * 512 + o0;
  const bf16* A1 = A + (rowBase + r1) * 512 + o1;
  const bf16* B0 = Bt + (size_t)(colBase + r0) * 512 + o0;
  const bf16* B1 = Bt + (size_t)(colBase + r1) * 512 + o1;

  const int wr = (w & 1) * 64;
  const int wc = (w >> 1) * 64;

  for (int kt = 0; kt < 16; ++kt) {
    const int k0 = kt * 32;
    __syncthreads();
    async_lds16(A0 + k0, sA + c0 * 8);
    async_lds16(A1 + k0, sA + c1 * 8);
    async_lds16(B0 + k0, sB + c0 * 8);
    async_lds16(B1 + k0, sB + c1 * 8);
    __syncthreads();
    bf16x8 a[4], b[4];
#pragma unroll
    for (int i = 0; i < 4; ++i)
      a[i] = *(const bf16x8*)(sA + (wr + i * 16 + fm) * 32 + fq * 8);
#pragma unroll
    for (int j = 0; j < 4; ++j)
      b[j] = *(const bf16x8*)(sB + (wc + j * 16 + fm) * 32 + fq * 8);
#pragma unroll
    for (int i = 0; i < 4; ++i)
#pragma unroll
      for (int j = 0; j < 4; ++j)
        acc[i][j] = MFMA16(a[i], b[j], acc[i][j]);
  }

  // epilogue; C/D layout: col = lane&15, row = (lane>>4)*4 + r
#pragma unroll
  for (int i = 0; i < 4; ++i) {
#pragma unroll
    for (int r = 0; r < 4; ++r) {
      const long R = rowBase + wr + i * 16 + fq * 4 + r;
      const float mk = mask ? (float)mask[R] : 1.0f;
      const bf16* resrow = resid ? resid + R * 512 : nullptr;
      bf16* outrow = out + R * 512;
#pragma unroll
      for (int j = 0; j < 4; ++j) {
        const int C = colBase + wc + j * 16 + fm;
        float v = acc[i][j][r] + (float)bias[C];
        if (mask) v *= mk;
        if (resid) v = (float)resrow[C] + fmaxf(v, 0.0f);
        outrow[C] = (bf16)v;
      }
    }
  }
}

// ---------------------------------------------------------------------------
// R12: Q projection with fused f32->bf16 A conversion, T14-scheduled.
// A-loads for kt+1 issued AFTER the compute barrier (latency overlaps
// MFMA; drained at next staging barrier where the cvt needs them).
// out = (A@Bt^T + bias) * mask[row].
// ---------------------------------------------------------------------------
__global__ __launch_bounds__(256, 2) void gemm512_f32A(
    const float* __restrict__ A, const bf16* __restrict__ Bt,
    const bf16* __restrict__ bias, const bf16* __restrict__ mask,
    bf16* __restrict__ out) {
  __shared__ bf16 sA[128 * 32];
  __shared__ bf16 sB[128 * 32];
  const int tid = threadIdx.x;
  const int lane = tid & 63;
  const int w = tid >> 6;
  const int fm = lane & 15;
  const int fq = lane >> 4;
  long rowBase; int colBase;
  swz512(blockIdx.x, rowBase, colBase);

  f32x4 acc[4][4] = {};

  const int c0 = tid, c1 = tid + 256;
  const int r0 = c0 >> 2, o0 = (c0 & 3) * 8;
  const int r1 = c1 >> 2, o1 = (c1 & 3) * 8;
  const float* A0 = A + (rowBase + r0) * 512 + o0;
  const float* A1 = A + (rowBase + r1) * 512 + o1;
  const bf16* B0 = Bt + (size_t)(colBase + r0) * 512 + o0;
  const bf16* B1 = Bt + (size_t)(colBase + r1) * 512 + o1;

  const int wr = (w & 1) * 64;
  const int wc = (w >> 1) * 64;

  // prefetch A regs for kt=0
  f32x4 x0 = *(const f32x4*)(A0);
  f32x4 x1 = *(const f32x4*)(A0 + 4);
  f32x4 y0 = *(const f32x4*)(A1);
  f32x4 y1 = *(const f32x4*)(A1 + 4);

  for (int kt = 0; kt < 16; ++kt) {
    __syncthreads();                       // prev compute done with sA/sB
    async_lds16(B0 + kt * 32, sB + c0 * 8);
    async_lds16(B1 + kt * 32, sB + c1 * 8);
    {
      bf16x8 va, vb;
#pragma unroll
      for (int j = 0; j < 4; ++j) {
        va[j] = (bf16)x0[j]; va[j + 4] = (bf16)x1[j];
        vb[j] = (bf16)y0[j]; vb[j + 4] = (bf16)y1[j];
      }
      *(bf16x8*)(sA + c0 * 8) = va;
      *(bf16x8*)(sA + c1 * 8) = vb;
    }
    __syncthreads();                       // B DMA + sA writes visible
    if (kt < 15) {                         // issue kt+1 A loads; latency
      const int k1 = kt * 32 + 32;         // overlaps the MFMAs below
      x0 = *(const f32x4*)(A0 + k1);
      x1 = *(const f32x4*)(A0 + k1 + 4);
      y0 = *(const f32x4*)(A1 + k1);
      y1 = *(const f32x4*)(A1 + k1 + 4);
    }
    bf16x8 a[4], b[4];
#pragma unroll
    for (int i = 0; i < 4; ++i)
      a[i] = *(const bf16x8*)(sA + (wr + i * 16 + fm) * 32 + fq * 8);
#pragma unroll
    for (int j = 0; j < 4; ++j)
      b[j] = *(const bf16x8*)(sB + (wc + j * 16 + fm) * 32 + fq * 8);
#pragma unroll
    for (int i = 0; i < 4; ++i)
#pragma unroll
      for (int j = 0; j < 4; ++j)
        acc[i][j] = MFMA16(a[i], b[j], acc[i][j]);
  }

#pragma unroll
  for (int i = 0; i < 4; ++i) {
#pragma unroll
    for (int r = 0; r < 4; ++r) {
      const long R = rowBase + wr + i * 16 + fq * 4 + r;
      const float mk = (float)mask[R];
      bf16* outrow = out + R * 512;
#pragma unroll
      for (int j = 0; j < 4; ++j) {
        const int C = colBase + wc + j * 16 + fm;
        outrow[C] = (bf16)((acc[i][j][r] + (float)bias[C]) * mk);
      }
    }
  }
}

// ---------------------------------------------------------------------------
// Fused K/V projection, f32 A with fused conversion, T14-scheduled (R12).
//   Kp[R][C] = (A@Tk^T + bk) * Km[R];  Vt[...] transposed V store.
// ---------------------------------------------------------------------------
__global__ __launch_bounds__(256, 2) void gemmKV_f32A(
    const float* __restrict__ A, const bf16* __restrict__ Btk,
    const bf16* __restrict__ Btv, const bf16* __restrict__ bk,
    const bf16* __restrict__ bv, const bf16* __restrict__ Km,
    bf16* __restrict__ Kp, bf16* __restrict__ Vt) {
  __shared__ bf16 sA[128 * 32];
  __shared__ bf16 sBk[128 * 32];
  __shared__ bf16 sBv[128 * 32];
  const int tid = threadIdx.x;
  const int lane = tid & 63;
  const int w = tid >> 6;
  const int fm = lane & 15;
  const int fq = lane >> 4;
  long rowBase; int colBase;
  swz512(blockIdx.x, rowBase, colBase);

  f32x4 acck[4][4] = {};
  f32x4 accv[4][4] = {};

  const int c0 = tid, c1 = tid + 256;
  const int r0 = c0 >> 2, o0 = (c0 & 3) * 8;
  const int r1 = c1 >> 2, o1 = (c1 & 3) * 8;
  const float* A0 = A + (rowBase + r0) * 512 + o0;
  const float* A1 = A + (rowBase + r1) * 512 + o1;
  const bf16* Bk0 = Btk + (size_t)(colBase + r0) * 512 + o0;
  const bf16* Bk1 = Btk + (size_t)(colBase + r1) * 512 + o1;
  const bf16* Bv0 = Btv + (size_t)(colBase + r0) * 512 + o0;
  const bf16* Bv1 = Btv + (size_t)(colBase + r1) * 512 + o1;

  const int wr = (w & 1) * 64;
  const int wc = (w >> 1) * 64;

  f32x4 x0 = *(const f32x4*)(A0);
  f32x4 x1 = *(const f32x4*)(A0 + 4);
  f32x4 y0 = *(const f32x4*)(A1);
  f32x4 y1 = *(const f32x4*)(A1 + 4);

  for (int kt = 0; kt < 16; ++kt) {
    const int k0 = kt * 32;
    __syncthreads();
    async_lds16(Bk0 + k0, sBk + c0 * 8);
    async_lds16(Bk1 + k0, sBk + c1 * 8);
    async_lds16(Bv0 + k0, sBv + c0 * 8);
    async_lds16(Bv1 + k0, sBv + c1 * 8);
    {
      bf16x8 va, vb;
#pragma unroll
      for (int j = 0; j < 4; ++j) {
        va[j] = (bf16)x0[j]; va[j + 4] = (bf16)x1[j];
        vb[j] = (bf16)y0[j]; vb[j + 4] = (bf16)y1[j];
      }
      *(bf16x8*)(sA + c0 * 8) = va;
      *(bf16x8*)(sA + c1 * 8) = vb;
    }
    __syncthreads();
    if (kt < 15) {
      const int k1 = k0 + 32;
      x0 = *(const f32x4*)(A0 + k1);
      x1 = *(const f32x4*)(A0 + k1 + 4);
      y0 = *(const f32x4*)(A1 + k1);
      y1 = *(const f32x4*)(A1 + k1 + 4);
    }
    bf16x8 a[4], b[4], bv2[4];
#pragma unroll
    for (int i = 0; i < 4; ++i)
      a[i] = *(const bf16x8*)(sA + (wr + i * 16 + fm) * 32 + fq * 8);
#pragma unroll
    for (int j = 0; j < 4; ++j) {
      b[j] = *(const bf16x8*)(sBk + (wc + j * 16 + fm) * 32 + fq * 8);
      bv2[j] = *(const bf16x8*)(sBv + (wc + j * 16 + fm) * 32 + fq * 8);
    }
#pragma unroll
    for (int i = 0; i < 4; ++i)
#pragma unroll
      for (int j = 0; j < 4; ++j) {
        acck[i][j] = MFMA16(a[i], b[j], acck[i][j]);
        accv[i][j] = MFMA16(a[i], bv2[j], accv[i][j]);
      }
  }

  const int bidx = (int)(rowBase >> 10);
#pragma unroll
  for (int i = 0; i < 4; ++i) {
#pragma unroll
    for (int r = 0; r < 4; ++r) {
      const long R = rowBase + wr + i * 16 + fq * 4 + r;
      const float mk = (float)Km[R];
      bf16* outrow = Kp + R * 512;
#pragma unroll
      for (int j = 0; j < 4; ++j) {
        const int C = colBase + wc + j * 16 + fm;
        outrow[C] = (bf16)((acck[i][j][r] + (float)bk[C]) * mk);
      }
    }
    // V: transposed store, r -> 4 consecutive kk (8B store)
    const int kkb = (int)(rowBase & 1023) + wr + i * 16 + fq * 4;
#pragma unroll
    for (int j = 0; j < 4; ++j) {
      const int C = colBase + wc + j * 16 + fm;
      const float bvc = (float)bv[C];
      bf16x4 pv;
#pragma unroll
      for (int r = 0; r < 4; ++r) pv[r] = (bf16)(accv[i][j][r] + bvc);
      bf16* dst = Vt + ((size_t)(bidx * 8 + (C >> 6)) * 64 + (C & 63)) * 1024 + kkb;
      *(bf16x4*)((void*)dst) = pv;
    }
  }
}

// ---------------------------------------------------------------------------
// Attention: 128-q-row blocks, wave owns 32 q-rows (2 subtiles of 16).
// Grid 1024 linear, XCD-swizzled (id&7==h). S^T MFMA: A=K rows, B=Q rows;
// kf/vf fragments shared across the 2 q-subtiles (halved LDS reads/MFMA).
// y = exp2(exp2(s*c1)*kml); binary Qm factored to epilogue.
// R12 = exact R9 (no setprio: m190 lockstep regime; R11 measured -4us).
// LDS 37.6KB, 4 blocks/CU. O in-place over Qp.
// ---------------------------------------------------------------------------
__global__ __launch_bounds__(256, 4) void attn_kernel(
    bf16* __restrict__ Qp, const bf16* __restrict__ Kp,
    const bf16* __restrict__ Vt, const bf16* __restrict__ Qm,
    const bf16* __restrict__ Km) {
  __shared__ bf16 sK[64][72];      // [kk][d]
  __shared__ bf16 sVt[64][72];     // [d][kk]
  __shared__ bf16 sX[4][32][72];   // per-wave [q][kk]
  __shared__ float sKl[64];        // km * log2e
  __shared__ float sL[4][32];

  const int tid = threadIdx.x;
  const int lane = tid & 63;
  const int w = tid >> 6;
  const int fm = lane & 15;
  const int fq = lane >> 4;
  const int id = blockIdx.x;
  const int bh = id & 127;         // id%8 == h -> XCD locality for K/V
  const int q0 = (id >> 7) * 128;
  const int b = bh >> 3;
  const int hh = bh & 7;

  bf16* Qbase = Qp + ((long)b * 1024 + q0) * 512 + hh * 64;
  float qm_lane[2];
  qm_lane[0] = (float)Qm[(long)b * 1024 + q0 + w * 32 + fm];
  qm_lane[1] = (float)Qm[(long)b * 1024 + q0 + w * 32 + 16 + fm];

  // loop-invariant Q fragments straight from global: [subtile u][ks]
  bf16x8 qf[2][2];
#pragma unroll
  for (int u = 0; u < 2; ++u)
#pragma unroll
    for (int ks = 0; ks < 2; ++ks)
      qf[u][ks] = *(const bf16x8*)(Qbase + (long)(w * 32 + u * 16 + fm) * 512 +
                                   ks * 32 + fq * 8);

  f32x4 acc_o[2][4] = {};
  float l_lane[2] = {0.f, 0.f};
  const float c1 = 0.063758715f;   // log2(e)/sqrt(512)
  const float LOG2E = 1.4426950408889634f;

  const bf16* Vthead = Vt + ((long)b * 8 + hh) * 64 * 1024;  // [d][kk]
  const bf16* Kbb = Kp + (long)b * 1024 * 512 + hh * 64;
  const bf16* Kmb = Km + (long)b * 1024;

  for (int kt = 0; kt < 16; ++kt) {
    const int kk0 = kt * 64;
    __syncthreads();
    const bf16* Kbase = Kbb + (long)kk0 * 512;
    for (int c = tid; c < 512; c += 256) {
      const int row = c >> 3, col = (c & 7) * 8;
      *(bf16x8*)(&sK[row][col]) = *(const bf16x8*)(Kbase + (long)row * 512 + col);
      *(bf16x8*)(&sVt[row][col]) =
          *(const bf16x8*)(Vthead + (long)row * 1024 + kk0 + col);
    }
    if (tid < 64) sKl[tid] = (float)Kmb[kk0 + tid] * LOG2E;
    __syncthreads();

    // S^T: C[kk 64][q 32]; A = K rows (m=kk), B = Q rows (n=q, 2 subtiles)
    f32x4 s_acc[2][4] = {};
#pragma unroll
    for (int ks = 0; ks < 2; ++ks)
#pragma unroll
      for (int t = 0; t < 4; ++t) {
        const bf16x8 kf = *(const bf16x8*)(&sK[t * 16 + fm][ks * 32 + fq * 8]);
        s_acc[0][t] = MFMA16(kf, qf[0][ks], s_acc[0][t]);
        s_acc[1][t] = MFMA16(kf, qf[1][ks], s_acc[1][t]);
      }
    // lane holds q=fm (subtile u), kk = t*16 + fq*4 + r
#pragma unroll
    for (int u = 0; u < 2; ++u)
#pragma unroll
      for (int t = 0; t < 4; ++t) {
        const f32x4 kml4 = *(const f32x4*)(&sKl[t * 16 + fq * 4]);
        bf16x4 xp;
#pragma unroll
        for (int r = 0; r < 4; ++r) {
          const float e1 = EXP2F(s_acc[u][t][r] * c1);
          const float y = EXP2F(e1 * kml4[r]);
          l_lane[u] += y;
          xp[r] = (bf16)y;
        }
        *(bf16x4*)((void*)&sX[w][u * 16 + fm][t * 16 + fq * 4]) = xp;
      }
    // PV: C[q 32][d 64]; A = sX rows (2 subtiles), B = sVt rows (shared)
#pragma unroll
    for (int ks = 0; ks < 2; ++ks) {
      const bf16x8 xf0 = *(const bf16x8*)(&sX[w][fm][ks * 32 + fq * 8]);
      const bf16x8 xf1 = *(const bf16x8*)(&sX[w][16 + fm][ks * 32 + fq * 8]);
#pragma unroll
      for (int t = 0; t < 4; ++t) {
        const bf16x8 vf = *(const bf16x8*)(&sVt[t * 16 + fm][ks * 32 + fq * 8]);
        acc_o[0][t] = MFMA16(xf0, vf, acc_o[0][t]);
        acc_o[1][t] = MFMA16(xf1, vf, acc_o[1][t]);
      }
    }
  }

  // per-q Y-sums
#pragma unroll
  for (int u = 0; u < 2; ++u) {
    l_lane[u] += __shfl_xor(l_lane[u], 16);
    l_lane[u] += __shfl_xor(l_lane[u], 32);
    if (fq == 0) sL[w][u * 16 + fm] = l_lane[u];
  }
  __syncthreads();

  // epilogue: lane holds q = u*16 + fq*4 + r, d = t*16 + fm (PV C-layout)
  // residual re-read from global; same-thread read-then-write, no hazard.
#pragma unroll
  for (int u = 0; u < 2; ++u) {
#pragma unroll
    for (int t = 0; t < 4; ++t) {
#pragma unroll
      for (int r = 0; r < 4; ++r) {
        const int qr = w * 32 + u * 16 + fq * 4 + r;
        const int dc = t * 16 + fm;
        const float qm_r = __shfl(qm_lane[u], fq * 4 + r, 64);
        const float li = 1.0f / (qm_r * sL[w][u * 16 + fq * 4 + r] + 1e-8f);
        const float val =
            (float)Qbase[(long)qr * 512 + dc] + qm_r * acc_o[u][t][r] * li;
        Qbase[(long)qr * 512 + dc] = (bf16)val;
      }
    }
  }
}

// ---------------------------------------------------------------------------
// LayerNorm (bf16 -> bf16). One wave per row. In-place safe.
// ---------------------------------------------------------------------------
__global__ __launch_bounds__(256) void lnorm(
    const bf16* __restrict__ X, const bf16* __restrict__ g,
    const bf16* __restrict__ bb, bf16* __restrict__ out) {
  const int row = blockIdx.x * 4 + (threadIdx.x >> 6);
  const int lane = threadIdx.x & 63;
  const bf16x8 v = *(const bf16x8*)(X + (size_t)row * 512 + lane * 8);
  float x[8], s = 0.f, ss = 0.f;
#pragma unroll
  for (int j = 0; j < 8; ++j) {
    x[j] = (float)v[j];
    s += x[j];
    ss += x[j] * x[j];
  }
#pragma unroll
  for (int m = 1; m < 64; m <<= 1) {
    s += __shfl_xor(s, m);
    ss += __shfl_xor(ss, m);
  }
  const float mean = s * (1.0f / 512.0f);
  const float var = ss * (1.0f / 512.0f) - mean * mean;
  const float rstd = 1.0f / sqrtf(var + 1e-5f);
  const bf16x8 gv = *(const bf16x8*)(g + lane * 8);
  const bf16x8 bv = *(const bf16x8*)(bb + lane * 8);
  bf16x8 o;
#pragma unroll
  for (int j = 0; j < 8; ++j)
    o[j] = (bf16)((x[j] - mean) * rstd * (float)gv[j] + (float)bv[j]);
  *(bf16x8*)(out + (size_t)row * 512 + lane * 8) = o;
}

// ---------------------------------------------------------------------------
// Final LayerNorm: bf16 in, f32 out.
// ---------------------------------------------------------------------------
__global__ __launch_bounds__(256) void lnorm_out(
    const bf16* __restrict__ X, const bf16* __restrict__ g,
    const bf16* __restrict__ bb, float* __restrict__ out) {
  const int row = blockIdx.x * 4 + (threadIdx.x >> 6);
  const int lane = threadIdx.x & 63;
  const bf16x8 v = *(const bf16x8*)(X + (size_t)row * 512 + lane * 8);
  float x[8], s = 0.f, ss = 0.f;
#pragma unroll
  for (int j = 0; j < 8; ++j) {
    x[j] = (float)v[j];
    s += x[j];
    ss += x[j] * x[j];
  }
#pragma unroll
  for (int m = 1; m < 64; m <<= 1) {
    s += __shfl_xor(s, m);
    ss += __shfl_xor(ss, m);
  }
  const float mean = s * (1.0f / 512.0f);
  const float var = ss * (1.0f / 512.0f) - mean * mean;
  const float rstd = 1.0f / sqrtf(var + 1e-5f);
  const bf16x8 gv = *(const bf16x8*)(g + lane * 8);
  const bf16x8 bv = *(const bf16x8*)(bb + lane * 8);
  f32x4 a, c;
#pragma unroll
  for (int j = 0; j < 4; ++j) {
    a[j] = (x[j] - mean) * rstd * (float)gv[j] + (float)bv[j];
    c[j] = (x[j + 4] - mean) * rstd * (float)gv[j + 4] + (float)bv[j + 4];
  }
  float* fo = out + (size_t)row * 512 + lane * 8;
  *(f32x4*)fo = a;
  *(f32x4*)(fo + 4) = c;
}

// ---------------------------------------------------------------------------
extern "C" void kernel_launch(void* const* d_in, const int* in_sizes, int n_in,
                              void* d_out, int out_size, void* d_ws, size_t ws_size,
                              hipStream_t stream) {
  (void)in_sizes; (void)n_in; (void)out_size; (void)ws_size;
  const float* Q = (const float*)d_in[0];
  const float* K = (const float*)d_in[1];

  bf16* ws = (bf16*)d_ws;
  const long W2 = 512L * 512;
  const long MN = 16384L * 512;
  bf16* Tq = ws;                           // 4 transposed bf16 weights: 2MB
  bf16* Tk = Tq + W2;
  bf16* Tv = Tk + W2;
  bf16* To = Tv + W2;
  bf16* sm = To + W2;                      // 8 x 512 smalls
  bf16* cQm = sm + 8 * 512;                // 16384
  bf16* cKm = cQm + 16384;                 // 16384
  bf16* Qp = cKm + 16384;                  // 16MB
  bf16* Kp = Qp + MN;                      // 16MB
  bf16* Vt = (bf16*)d_out + MN;            // V^T in d_out upper 16MB

  bf16* cbq = sm + 0 * 512;
  bf16* cbk = sm + 1 * 512;
  bf16* cbv = sm + 2 * 512;
  bf16* cbo = sm + 3 * 512;
  bf16* cg0 = sm + 4 * 512;
  bf16* cb0 = sm + 5 * 512;
  bf16* cg1 = sm + 6 * 512;
  bf16* cb1 = sm + 7 * 512;

  transposeW<<<dim3(8, 8, 4), 256, 0, stream>>>(
      (const float*)d_in[4], (const float*)d_in[6],
      (const float*)d_in[8], (const float*)d_in[10], Tq, Tk, Tv, To);

  ConvArgs ca;
  ca.src[0] = (const float*)d_in[2];  ca.dst[0] = cQm; ca.n[0] = 16384;
  ca.src[1] = (const float*)d_in[3];  ca.dst[1] = cKm; ca.n[1] = 16384;
  ca.src[2] = (const float*)d_in[5];  ca.dst[2] = cbq; ca.n[2] = 512;
  ca.src[3] = (const float*)d_in[7];  ca.dst[3] = cbk; ca.n[3] = 512;
  ca.src[4] = (const float*)d_in[9];  ca.dst[4] = cbv; ca.n[4] = 512;
  ca.src[5] = (const float*)d_in[11]; ca.dst[5] = cbo; ca.n[5] = 512;
  ca.src[6] = (const float*)d_in[12]; ca.dst[6] = cg0; ca.n[6] = 512;
  ca.src[7] = (const float*)d_in[13]; ca.dst[7] = cb0; ca.n[7] = 512;
  ca.src[8] = (const float*)d_in[14]; ca.dst[8] = cg1; ca.n[8] = 512;
  ca.src[9] = (const float*)d_in[15]; ca.dst[9] = cb1; ca.n[9] = 512;
  convert_all<<<dim3(8, 1, 10), 256, 0, stream>>>(ca);

  gemm512_f32A<<<512, 256, 0, stream>>>(Q, Tq, cbq, cQm, Qp);
  gemmKV_f32A<<<512, 256, 0, stream>>>(K, Tk, Tv, cbk, cbv, cKm, Kp, Vt);

  attn_kernel<<<1024, 256, 0, stream>>>(Qp, Kp, Vt, cQm, cKm);

  lnorm<<<4096, 256, 0, stream>>>(Qp, cg0, cb0, Qp);
  gemm512<<<512, 256, 0, stream>>>(Qp, To, cbo, nullptr, Qp, Kp);
  lnorm_out<<<4096, 256, 0, stream>>>(Kp, cg1, cb1, (float*)d_out);
}

// Round 7
// 285.579 us; speedup vs baseline: 1.0907x; 1.0197x over previous
//
#include <hip/hip_runtime.h>
#include <hip/hip_bf16.h>
#include <cstdint>

// ---------------------------------------------------------------------------
// MAB block (f32 in/out, bf16 internal):
//   Qp=(Q@Wq+bq)*Qm; Kp=(K@Wk+bk)*Km; V=K@Wv+bv
//   S = Qh Kh^T / sqrt(512);  X = exp(exp(S)*Km)*Qm;  A = X/(sum+1e-8)
//   O = Qh + A@Vh;  O = LN0(O);  O = O + relu(O@Wo+bo);  out = LN1(O)
//
// R9:  attn 2->4 blocks/CU (sQ dropped). 81 -> 74 us.
// R10: FAILED reg-staged T14 in attn (unified reg file full -> spill).
// R11: setprio in attn HURT (lockstep waves, m190 regime). Removed.
// R12: f32A GEMMs w/ T14 A-prefetch: attn back to 74; GEMMs neutral.
// R13: (1) attn kt-ROTATION de-sync: blocks walk K/V tiles in rotated
//      order (rot=(id>>3)&15). Legal: no running max -- l/acc_o are
//      order-independent sums. Same-head blocks share rot (L2 locality
//      kept); co-resident different-head blocks land in different
//      phases -> softmax VALU overlaps staging LDS across blocks.
//      (2) proj_all = Q-proj + KV-proj merged (1024 blocks, tail-fill).
//      (3) prep = transposeW + convert_all merged.
// R14: identical resubmission -- round 6 bench was an infra failure
//      (container acquisition); R13 never measured.
// Buffers: ws ~36MB (T, smalls, masks, Qp, Kp); d_out upper 16MB = Vt
// (dead before final LN writes).
// ---------------------------------------------------------------------------

typedef __bf16 bf16;
typedef __bf16 bf16x4 __attribute__((ext_vector_type(4)));
typedef __bf16 bf16x8 __attribute__((ext_vector_type(8)));
typedef float f32x4 __attribute__((ext_vector_type(4)));

#define MFMA16(a, b, c) __builtin_amdgcn_mfma_f32_16x16x32_bf16((a), (b), (c), 0, 0, 0)

#if __has_builtin(__builtin_amdgcn_exp2f)
#define EXP2F(x) __builtin_amdgcn_exp2f(x)
#else
#define EXP2F(x) exp2f(x)
#endif

static __device__ __forceinline__ void async_lds16(const bf16* g, bf16* l) {
  __builtin_amdgcn_global_load_lds(
      (__attribute__((address_space(1))) void*)(void*)g,
      (__attribute__((address_space(3))) void*)l,
      16, 0, 0);
}

// XCD swizzle for 512-block GEMM grids: 4 col-blocks of one row share id&7.
static __device__ __forceinline__ void swz512(int id, long& rowBase, int& colBase) {
  colBase = ((id >> 3) & 3) * 128;
  rowBase = (long)((id & 7) + 8 * (id >> 5)) * 128;
}

// ---------------------------------------------------------------------------
// Batched f32->bf16 conversion args (10 small arrays).
// ---------------------------------------------------------------------------
struct ConvArgs {
  const float* src[10];
  bf16* dst[10];
  int n[10];
};

// ---------------------------------------------------------------------------
// R13 prep: ids 0..255 = weight transpose (4 x 512x512); 256..335 = converts.
// T[n][k] = (bf16)W[k][n].
// ---------------------------------------------------------------------------
__global__ __launch_bounds__(256) void prep(
    const float* __restrict__ Wq, const float* __restrict__ Wk,
    const float* __restrict__ Wv, const float* __restrict__ Wo,
    bf16* __restrict__ Tq, bf16* __restrict__ Tk,
    bf16* __restrict__ Tv, bf16* __restrict__ To, ConvArgs ca) {
  __shared__ bf16 t[64][72];
  const int id = blockIdx.x;
  const int tid = threadIdx.x;
  if (id < 256) {
    const int bx = id & 7, by = (id >> 3) & 7, bz = id >> 6;
    const float* src;
    bf16* dst;
    switch (bz) {
      case 0: src = Wq; dst = Tq; break;
      case 1: src = Wk; dst = Tk; break;
      case 2: src = Wv; dst = Tv; break;
      default: src = Wo; dst = To; break;
    }
    const int n0 = bx * 64;
    const int k0 = by * 64;
    for (int c = tid; c < 512; c += 256) {
      const int row = c >> 3, col = (c & 7) * 8;   // row: k, col: n
      const float* sp = src + (size_t)(k0 + row) * 512 + n0 + col;
      const f32x4 a = *(const f32x4*)sp;
      const f32x4 b = *(const f32x4*)(sp + 4);
      bf16x8 v;
#pragma unroll
      for (int j = 0; j < 4; ++j) { v[j] = (bf16)a[j]; v[j + 4] = (bf16)b[j]; }
      *(bf16x8*)(&t[row][col]) = v;
    }
    __syncthreads();
    for (int c = tid; c < 512; c += 256) {
      const int row = c >> 3, col8 = (c & 7) * 8;  // row: n, col8: k
      bf16x8 v;
#pragma unroll
      for (int j = 0; j < 8; ++j) v[j] = t[col8 + j][row];
      *(bf16x8*)(dst + (size_t)(n0 + row) * 512 + k0 + col8) = v;
    }
  } else {
    const int cid = id - 256;
    const int seg = cid >> 3;
    const int n = ca.n[seg];
    const long i = ((long)(cid & 7) * 256 + tid) * 8;
    if (i >= n) return;
    const float* s = ca.src[seg];
    const f32x4 x0 = *(const f32x4*)(s + i);
    const f32x4 x1 = *(const f32x4*)(s + i + 4);
    bf16x8 o;
#pragma unroll
    for (int j = 0; j < 4; ++j) { o[j] = (bf16)x0[j]; o[j + 4] = (bf16)x1[j]; }
    *(bf16x8*)(ca.dst[seg] + i) = o;
  }
}

// ---------------------------------------------------------------------------
// GEMM (bf16 A): out[M x 512] = epilogue(A @ Bt^T + bias).
//   mask != null : out = (acc+bias) * mask[row]
//   resid != null: out = resid + relu(acc+bias)
// m97 structure; XCD-swizzled linear grid (512 blocks).
// ---------------------------------------------------------------------------
__global__ __launch_bounds__(256, 2) void gemm512(
    const bf16* __restrict__ A, const bf16* __restrict__ Bt,
    const bf16* __restrict__ bias, const bf16* __restrict__ mask,
    const bf16* __restrict__ resid, bf16* __restrict__ out) {
  __shared__ bf16 sA[128 * 32];
  __shared__ bf16 sB[128 * 32];
  const int tid = threadIdx.x;
  const int lane = tid & 63;
  const int w = tid >> 6;
  const int fm = lane & 15;
  const int fq = lane >> 4;
  long rowBase; int colBase;
  swz512(blockIdx.x, rowBase, colBase);

  f32x4 acc[4][4] = {};

  const int c0 = tid, c1 = tid + 256;
  const int r0 = c0 >> 2, o0 = (c0 & 3) * 8;
  const int r1 = c1 >> 2, o1 = (c1 & 3) * 8;
  const bf16* A0 = A + (rowBase + r0) * 512 + o0;
  const bf16* A1 = A + (rowBase + r1) * 512 + o1;
  const bf16* B0 = Bt + (size_t)(colBase + r0) * 512 + o0;
  const bf16* B1 = Bt + (size_t)(colBase + r1) * 512 + o1;

  const int wr = (w & 1) * 64;
  const int wc = (w >> 1) * 64;

  for (int kt = 0; kt < 16; ++kt) {
    const int k0 = kt * 32;
    __syncthreads();
    async_lds16(A0 + k0, sA + c0 * 8);
    async_lds16(A1 + k0, sA + c1 * 8);
    async_lds16(B0 + k0, sB + c0 * 8);
    async_lds16(B1 + k0, sB + c1 * 8);
    __syncthreads();
    bf16x8 a[4], b[4];
#pragma unroll
    for (int i = 0; i < 4; ++i)
      a[i] = *(const bf16x8*)(sA + (wr + i * 16 + fm) * 32 + fq * 8);
#pragma unroll
    for (int j = 0; j < 4; ++j)
      b[j] = *(const bf16x8*)(sB + (wc + j * 16 + fm) * 32 + fq * 8);
#pragma unroll
    for (int i = 0; i < 4; ++i)
#pragma unroll
      for (int j = 0; j < 4; ++j)
        acc[i][j] = MFMA16(a[i], b[j], acc[i][j]);
  }

  // epilogue; C/D layout: col = lane&15, row = (lane>>4)*4 + r
#pragma unroll
  for (int i = 0; i < 4; ++i) {
#pragma unroll
    for (int r = 0; r < 4; ++r) {
      const long R = rowBase + wr + i * 16 + fq * 4 + r;
      const float mk = mask ? (float)mask[R] : 1.0f;
      const bf16* resrow = resid ? resid + R * 512 : nullptr;
      bf16* outrow = out + R * 512;
#pragma unroll
      for (int j = 0; j < 4; ++j) {
        const int C = colBase + wc + j * 16 + fm;
        float v = acc[i][j][r] + (float)bias[C];
        if (mask) v *= mk;
        if (resid) v = (float)resrow[C] + fmaxf(v, 0.0f);
        outrow[C] = (bf16)v;
      }
    }
  }
}

// ---------------------------------------------------------------------------
// R13 proj_all: ids 0..511 = Q projection (f32 A, fused cvt, T14 prefetch);
// ids 512..1023 = fused K/V projection. One launch -> tail-fill overlap.
// ---------------------------------------------------------------------------
__global__ __launch_bounds__(256, 2) void proj_all(
    const float* __restrict__ Qf, const float* __restrict__ Kf,
    const bf16* __restrict__ Tq, const bf16* __restrict__ Tk,
    const bf16* __restrict__ Tv, const bf16* __restrict__ bq,
    const bf16* __restrict__ bk, const bf16* __restrict__ bv,
    const bf16* __restrict__ Qm, const bf16* __restrict__ Km,
    bf16* __restrict__ Qp, bf16* __restrict__ Kp, bf16* __restrict__ Vt) {
  __shared__ bf16 sA[128 * 32];
  __shared__ bf16 sB1[128 * 32];
  __shared__ bf16 sB2[128 * 32];
  const int tid = threadIdx.x;
  const int lane = tid & 63;
  const int w = tid >> 6;
  const int fm = lane & 15;
  const int fq = lane >> 4;
  const int wr = (w & 1) * 64;
  const int wc = (w >> 1) * 64;
  const int c0 = tid, c1 = tid + 256;
  const int r0 = c0 >> 2, o0 = (c0 & 3) * 8;
  const int r1 = c1 >> 2, o1 = (c1 & 3) * 8;

  if (blockIdx.x < 512) {
    // ---- Q projection ----
    long rowBase; int colBase;
    swz512(blockIdx.x, rowBase, colBase);
    f32x4 acc[4][4] = {};
    const float* A0 = Qf + (rowBase + r0) * 512 + o0;
    const float* A1 = Qf + (rowBase + r1) * 512 + o1;
    const bf16* B0 = Tq + (size_t)(colBase + r0) * 512 + o0;
    const bf16* B1 = Tq + (size_t)(colBase + r1) * 512 + o1;

    f32x4 x0 = *(const f32x4*)(A0);
    f32x4 x1 = *(const f32x4*)(A0 + 4);
    f32x4 y0 = *(const f32x4*)(A1);
    f32x4 y1 = *(const f32x4*)(A1 + 4);

    for (int kt = 0; kt < 16; ++kt) {
      __syncthreads();
      async_lds16(B0 + kt * 32, sB1 + c0 * 8);
      async_lds16(B1 + kt * 32, sB1 + c1 * 8);
      {
        bf16x8 va, vb;
#pragma unroll
        for (int j = 0; j < 4; ++j) {
          va[j] = (bf16)x0[j]; va[j + 4] = (bf16)x1[j];
          vb[j] = (bf16)y0[j]; vb[j + 4] = (bf16)y1[j];
        }
        *(bf16x8*)(sA + c0 * 8) = va;
        *(bf16x8*)(sA + c1 * 8) = vb;
      }
      __syncthreads();
      if (kt < 15) {
        const int k1 = kt * 32 + 32;
        x0 = *(const f32x4*)(A0 + k1);
        x1 = *(const f32x4*)(A0 + k1 + 4);
        y0 = *(const f32x4*)(A1 + k1);
        y1 = *(const f32x4*)(A1 + k1 + 4);
      }
      bf16x8 a[4], b[4];
#pragma unroll
      for (int i = 0; i < 4; ++i)
        a[i] = *(const bf16x8*)(sA + (wr + i * 16 + fm) * 32 + fq * 8);
#pragma unroll
      for (int j = 0; j < 4; ++j)
        b[j] = *(const bf16x8*)(sB1 + (wc + j * 16 + fm) * 32 + fq * 8);
#pragma unroll
      for (int i = 0; i < 4; ++i)
#pragma unroll
        for (int j = 0; j < 4; ++j)
          acc[i][j] = MFMA16(a[i], b[j], acc[i][j]);
    }

#pragma unroll
    for (int i = 0; i < 4; ++i) {
#pragma unroll
      for (int r = 0; r < 4; ++r) {
        const long R = rowBase + wr + i * 16 + fq * 4 + r;
        const float mk = (float)Qm[R];
        bf16* outrow = Qp + R * 512;
#pragma unroll
        for (int j = 0; j < 4; ++j) {
          const int C = colBase + wc + j * 16 + fm;
          outrow[C] = (bf16)((acc[i][j][r] + (float)bq[C]) * mk);
        }
      }
    }
  } else {
    // ---- fused K/V projection ----
    long rowBase; int colBase;
    swz512(blockIdx.x - 512, rowBase, colBase);
    f32x4 acck[4][4] = {};
    f32x4 accv[4][4] = {};
    const float* A0 = Kf + (rowBase + r0) * 512 + o0;
    const float* A1 = Kf + (rowBase + r1) * 512 + o1;
    const bf16* Bk0 = Tk + (size_t)(colBase + r0) * 512 + o0;
    const bf16* Bk1 = Tk + (size_t)(colBase + r1) * 512 + o1;
    const bf16* Bv0 = Tv + (size_t)(colBase + r0) * 512 + o0;
    const bf16* Bv1 = Tv + (size_t)(colBase + r1) * 512 + o1;

    f32x4 x0 = *(const f32x4*)(A0);
    f32x4 x1 = *(const f32x4*)(A0 + 4);
    f32x4 y0 = *(const f32x4*)(A1);
    f32x4 y1 = *(const f32x4*)(A1 + 4);

    for (int kt = 0; kt < 16; ++kt) {
      const int k0 = kt * 32;
      __syncthreads();
      async_lds16(Bk0 + k0, sB1 + c0 * 8);
      async_lds16(Bk1 + k0, sB1 + c1 * 8);
      async_lds16(Bv0 + k0, sB2 + c0 * 8);
      async_lds16(Bv1 + k0, sB2 + c1 * 8);
      {
        bf16x8 va, vb;
#pragma unroll
        for (int j = 0; j < 4; ++j) {
          va[j] = (bf16)x0[j]; va[j + 4] = (bf16)x1[j];
          vb[j] = (bf16)y0[j]; vb[j + 4] = (bf16)y1[j];
        }
        *(bf16x8*)(sA + c0 * 8) = va;
        *(bf16x8*)(sA + c1 * 8) = vb;
      }
      __syncthreads();
      if (kt < 15) {
        const int k1 = k0 + 32;
        x0 = *(const f32x4*)(A0 + k1);
        x1 = *(const f32x4*)(A0 + k1 + 4);
        y0 = *(const f32x4*)(A1 + k1);
        y1 = *(const f32x4*)(A1 + k1 + 4);
      }
      bf16x8 a[4], b[4], bv2[4];
#pragma unroll
      for (int i = 0; i < 4; ++i)
        a[i] = *(const bf16x8*)(sA + (wr + i * 16 + fm) * 32 + fq * 8);
#pragma unroll
      for (int j = 0; j < 4; ++j) {
        b[j] = *(const bf16x8*)(sB1 + (wc + j * 16 + fm) * 32 + fq * 8);
        bv2[j] = *(const bf16x8*)(sB2 + (wc + j * 16 + fm) * 32 + fq * 8);
      }
#pragma unroll
      for (int i = 0; i < 4; ++i)
#pragma unroll
        for (int j = 0; j < 4; ++j) {
          acck[i][j] = MFMA16(a[i], b[j], acck[i][j]);
          accv[i][j] = MFMA16(a[i], bv2[j], accv[i][j]);
        }
    }

    const int bidx = (int)(rowBase >> 10);
#pragma unroll
    for (int i = 0; i < 4; ++i) {
#pragma unroll
      for (int r = 0; r < 4; ++r) {
        const long R = rowBase + wr + i * 16 + fq * 4 + r;
        const float mk = (float)Km[R];
        bf16* outrow = Kp + R * 512;
#pragma unroll
        for (int j = 0; j < 4; ++j) {
          const int C = colBase + wc + j * 16 + fm;
          outrow[C] = (bf16)((acck[i][j][r] + (float)bk[C]) * mk);
        }
      }
      // V: transposed store, r -> 4 consecutive kk (8B store)
      const int kkb = (int)(rowBase & 1023) + wr + i * 16 + fq * 4;
#pragma unroll
      for (int j = 0; j < 4; ++j) {
        const int C = colBase + wc + j * 16 + fm;
        const float bvc = (float)bv[C];
        bf16x4 pv;
#pragma unroll
        for (int r = 0; r < 4; ++r) pv[r] = (bf16)(accv[i][j][r] + bvc);
        bf16* dst =
            Vt + ((size_t)(bidx * 8 + (C >> 6)) * 64 + (C & 63)) * 1024 + kkb;
        *(bf16x4*)((void*)dst) = pv;
      }
    }
  }
}

// ---------------------------------------------------------------------------
// Attention: 128-q-row blocks, wave owns 32 q-rows (2 subtiles of 16).
// Grid 1024 linear, XCD-swizzled (id&7==h). S^T MFMA: A=K rows, B=Q rows;
// kf/vf fragments shared across the 2 q-subtiles. y=exp2(exp2(s*c1)*kml).
// R13: kt-ROTATION de-sync: kt_phys = (kt+rot)&15, rot=(id>>3)&15.
// Legal (order-independent sums); same-head blocks share rot -> L2 kept;
// co-resident blocks desync -> cross-block phase overlap.
// LDS 37.6KB, 4 blocks/CU. O in-place over Qp.
// ---------------------------------------------------------------------------
__global__ __launch_bounds__(256, 4) void attn_kernel(
    bf16* __restrict__ Qp, const bf16* __restrict__ Kp,
    const bf16* __restrict__ Vt, const bf16* __restrict__ Qm,
    const bf16* __restrict__ Km) {
  __shared__ bf16 sK[64][72];      // [kk][d]
  __shared__ bf16 sVt[64][72];     // [d][kk]
  __shared__ bf16 sX[4][32][72];   // per-wave [q][kk]
  __shared__ float sKl[64];        // km * log2e
  __shared__ float sL[4][32];

  const int tid = threadIdx.x;
  const int lane = tid & 63;
  const int w = tid >> 6;
  const int fm = lane & 15;
  const int fq = lane >> 4;
  const int id = blockIdx.x;
  const int bh = id & 127;         // id%8 == h -> XCD locality for K/V
  const int q0 = (id >> 7) * 128;
  const int b = bh >> 3;
  const int hh = bh & 7;
  const int rot = (id >> 3) & 15;  // same for same-head blocks

  bf16* Qbase = Qp + ((long)b * 1024 + q0) * 512 + hh * 64;
  float qm_lane[2];
  qm_lane[0] = (float)Qm[(long)b * 1024 + q0 + w * 32 + fm];
  qm_lane[1] = (float)Qm[(long)b * 1024 + q0 + w * 32 + 16 + fm];

  // loop-invariant Q fragments straight from global: [subtile u][ks]
  bf16x8 qf[2][2];
#pragma unroll
  for (int u = 0; u < 2; ++u)
#pragma unroll
    for (int ks = 0; ks < 2; ++ks)
      qf[u][ks] = *(const bf16x8*)(Qbase + (long)(w * 32 + u * 16 + fm) * 512 +
                                   ks * 32 + fq * 8);

  f32x4 acc_o[2][4] = {};
  float l_lane[2] = {0.f, 0.f};
  const float c1 = 0.063758715f;   // log2(e)/sqrt(512)
  const float LOG2E = 1.4426950408889634f;

  const bf16* Vthead = Vt + ((long)b * 8 + hh) * 64 * 1024;  // [d][kk]
  const bf16* Kbb = Kp + (long)b * 1024 * 512 + hh * 64;
  const bf16* Kmb = Km + (long)b * 1024;

  for (int kt = 0; kt < 16; ++kt) {
    const int kk0 = ((kt + rot) & 15) * 64;
    __syncthreads();
    const bf16* Kbase = Kbb + (long)kk0 * 512;
    for (int c = tid; c < 512; c += 256) {
      const int row = c >> 3, col = (c & 7) * 8;
      *(bf16x8*)(&sK[row][col]) = *(const bf16x8*)(Kbase + (long)row * 512 + col);
      *(bf16x8*)(&sVt[row][col]) =
          *(const bf16x8*)(Vthead + (long)row * 1024 + kk0 + col);
    }
    if (tid < 64) sKl[tid] = (float)Kmb[kk0 + tid] * LOG2E;
    __syncthreads();

    // S^T: C[kk 64][q 32]; A = K rows (m=kk), B = Q rows (n=q, 2 subtiles)
    f32x4 s_acc[2][4] = {};
#pragma unroll
    for (int ks = 0; ks < 2; ++ks)
#pragma unroll
      for (int t = 0; t < 4; ++t) {
        const bf16x8 kf = *(const bf16x8*)(&sK[t * 16 + fm][ks * 32 + fq * 8]);
        s_acc[0][t] = MFMA16(kf, qf[0][ks], s_acc[0][t]);
        s_acc[1][t] = MFMA16(kf, qf[1][ks], s_acc[1][t]);
      }
    // lane holds q=fm (subtile u), kk = t*16 + fq*4 + r
#pragma unroll
    for (int u = 0; u < 2; ++u)
#pragma unroll
      for (int t = 0; t < 4; ++t) {
        const f32x4 kml4 = *(const f32x4*)(&sKl[t * 16 + fq * 4]);
        bf16x4 xp;
#pragma unroll
        for (int r = 0; r < 4; ++r) {
          const float e1 = EXP2F(s_acc[u][t][r] * c1);
          const float y = EXP2F(e1 * kml4[r]);
          l_lane[u] += y;
          xp[r] = (bf16)y;
        }
        *(bf16x4*)((void*)&sX[w][u * 16 + fm][t * 16 + fq * 4]) = xp;
      }
    // PV: C[q 32][d 64]; A = sX rows (2 subtiles), B = sVt rows (shared)
#pragma unroll
    for (int ks = 0; ks < 2; ++ks) {
      const bf16x8 xf0 = *(const bf16x8*)(&sX[w][fm][ks * 32 + fq * 8]);
      const bf16x8 xf1 = *(const bf16x8*)(&sX[w][16 + fm][ks * 32 + fq * 8]);
#pragma unroll
      for (int t = 0; t < 4; ++t) {
        const bf16x8 vf = *(const bf16x8*)(&sVt[t * 16 + fm][ks * 32 + fq * 8]);
        acc_o[0][t] = MFMA16(xf0, vf, acc_o[0][t]);
        acc_o[1][t] = MFMA16(xf1, vf, acc_o[1][t]);
      }
    }
  }

  // per-q Y-sums
#pragma unroll
  for (int u = 0; u < 2; ++u) {
    l_lane[u] += __shfl_xor(l_lane[u], 16);
    l_lane[u] += __shfl_xor(l_lane[u], 32);
    if (fq == 0) sL[w][u * 16 + fm] = l_lane[u];
  }
  __syncthreads();

  // epilogue: lane holds q = u*16 + fq*4 + r, d = t*16 + fm (PV C-layout)
  // residual re-read from global; same-thread read-then-write, no hazard.
#pragma unroll
  for (int u = 0; u < 2; ++u) {
#pragma unroll
    for (int t = 0; t < 4; ++t) {
#pragma unroll
      for (int r = 0; r < 4; ++r) {
        const int qr = w * 32 + u * 16 + fq * 4 + r;
        const int dc = t * 16 + fm;
        const float qm_r = __shfl(qm_lane[u], fq * 4 + r, 64);
        const float li = 1.0f / (qm_r * sL[w][u * 16 + fq * 4 + r] + 1e-8f);
        const float val =
            (float)Qbase[(long)qr * 512 + dc] + qm_r * acc_o[u][t][r] * li;
        Qbase[(long)qr * 512 + dc] = (bf16)val;
      }
    }
  }
}

// ---------------------------------------------------------------------------
// LayerNorm (bf16 -> bf16). One wave per row. In-place safe.
// ---------------------------------------------------------------------------
__global__ __launch_bounds__(256) void lnorm(
    const bf16* __restrict__ X, const bf16* __restrict__ g,
    const bf16* __restrict__ bb, bf16* __restrict__ out) {
  const int row = blockIdx.x * 4 + (threadIdx.x >> 6);
  const int lane = threadIdx.x & 63;
  const bf16x8 v = *(const bf16x8*)(X + (size_t)row * 512 + lane * 8);
  float x[8], s = 0.f, ss = 0.f;
#pragma unroll
  for (int j = 0; j < 8; ++j) {
    x[j] = (float)v[j];
    s += x[j];
    ss += x[j] * x[j];
  }
#pragma unroll
  for (int m = 1; m < 64; m <<= 1) {
    s += __shfl_xor(s, m);
    ss += __shfl_xor(ss, m);
  }
  const float mean = s * (1.0f / 512.0f);
  const float var = ss * (1.0f / 512.0f) - mean * mean;
  const float rstd = 1.0f / sqrtf(var + 1e-5f);
  const bf16x8 gv = *(const bf16x8*)(g + lane * 8);
  const bf16x8 bv = *(const bf16x8*)(bb + lane * 8);
  bf16x8 o;
#pragma unroll
  for (int j = 0; j < 8; ++j)
    o[j] = (bf16)((x[j] - mean) * rstd * (float)gv[j] + (float)bv[j]);
  *(bf16x8*)(out + (size_t)row * 512 + lane * 8) = o;
}

// ---------------------------------------------------------------------------
// Final LayerNorm: bf16 in, f32 out.
// ---------------------------------------------------------------------------
__global__ __launch_bounds__(256) void lnorm_out(
    const bf16* __restrict__ X, const bf16* __restrict__ g,
    const bf16* __restrict__ bb, float* __restrict__ out) {
  const int row = blockIdx.x * 4 + (threadIdx.x >> 6);
  const int lane = threadIdx.x & 63;
  const bf16x8 v = *(const bf16x8*)(X + (size_t)row * 512 + lane * 8);
  float x[8], s = 0.f, ss = 0.f;
#pragma unroll
  for (int j = 0; j < 8; ++j) {
    x[j] = (float)v[j];
    s += x[j];
    ss += x[j] * x[j];
  }
#pragma unroll
  for (int m = 1; m < 64; m <<= 1) {
    s += __shfl_xor(s, m);
    ss += __shfl_xor(ss, m);
  }
  const float mean = s * (1.0f / 512.0f);
  const float var = ss * (1.0f / 512.0f) - mean * mean;
  const float rstd = 1.0f / sqrtf(var + 1e-5f);
  const bf16x8 gv = *(const bf16x8*)(g + lane * 8);
  const bf16x8 bv = *(const bf16x8*)(bb + lane * 8);
  f32x4 a, c;
#pragma unroll
  for (int j = 0; j < 4; ++j) {
    a[j] = (x[j] - mean) * rstd * (float)gv[j] + (float)bv[j];
    c[j] = (x[j + 4] - mean) * rstd * (float)gv[j + 4] + (float)bv[j + 4];
  }
  float* fo = out + (size_t)row * 512 + lane * 8;
  *(f32x4*)fo = a;
  *(f32x4*)(fo + 4) = c;
}

// ---------------------------------------------------------------------------
extern "C" void kernel_launch(void* const* d_in, const int* in_sizes, int n_in,
                              void* d_out, int out_size, void* d_ws, size_t ws_size,
                              hipStream_t stream) {
  (void)in_sizes; (void)n_in; (void)out_size; (void)ws_size;
  const float* Q = (const float*)d_in[0];
  const float* K = (const float*)d_in[1];

  bf16* ws = (bf16*)d_ws;
  const long W2 = 512L * 512;
  const long MN = 16384L * 512;
  bf16* Tq = ws;                           // 4 transposed bf16 weights: 2MB
  bf16* Tk = Tq + W2;
  bf16* Tv = Tk + W2;
  bf16* To = Tv + W2;
  bf16* sm = To + W2;                      // 8 x 512 smalls
  bf16* cQm = sm + 8 * 512;                // 16384
  bf16* cKm = cQm + 16384;                 // 16384
  bf16* Qp = cKm + 16384;                  // 16MB
  bf16* Kp = Qp + MN;                      // 16MB
  bf16* Vt = (bf16*)d_out + MN;            // V^T in d_out upper 16MB

  bf16* cbq = sm + 0 * 512;
  bf16* cbk = sm + 1 * 512;
  bf16* cbv = sm + 2 * 512;
  bf16* cbo = sm + 3 * 512;
  bf16* cg0 = sm + 4 * 512;
  bf16* cb0 = sm + 5 * 512;
  bf16* cg1 = sm + 6 * 512;
  bf16* cb1 = sm + 7 * 512;

  ConvArgs ca;
  ca.src[0] = (const float*)d_in[2];  ca.dst[0] = cQm; ca.n[0] = 16384;
  ca.src[1] = (const float*)d_in[3];  ca.dst[1] = cKm; ca.n[1] = 16384;
  ca.src[2] = (const float*)d_in[5];  ca.dst[2] = cbq; ca.n[2] = 512;
  ca.src[3] = (const float*)d_in[7];  ca.dst[3] = cbk; ca.n[3] = 512;
  ca.src[4] = (const float*)d_in[9];  ca.dst[4] = cbv; ca.n[4] = 512;
  ca.src[5] = (const float*)d_in[11]; ca.dst[5] = cbo; ca.n[5] = 512;
  ca.src[6] = (const float*)d_in[12]; ca.dst[6] = cg0; ca.n[6] = 512;
  ca.src[7] = (const float*)d_in[13]; ca.dst[7] = cb0; ca.n[7] = 512;
  ca.src[8] = (const float*)d_in[14]; ca.dst[8] = cg1; ca.n[8] = 512;
  ca.src[9] = (const float*)d_in[15]; ca.dst[9] = cb1; ca.n[9] = 512;

  prep<<<336, 256, 0, stream>>>(
      (const float*)d_in[4], (const float*)d_in[6],
      (const float*)d_in[8], (const float*)d_in[10], Tq, Tk, Tv, To, ca);

  proj_all<<<1024, 256, 0, stream>>>(Q, K, Tq, Tk, Tv, cbq, cbk, cbv,
                                     cQm, cKm, Qp, Kp, Vt);

  attn_kernel<<<1024, 256, 0, stream>>>(Qp, Kp, Vt, cQm, cKm);

  lnorm<<<4096, 256, 0, stream>>>(Qp, cg0, cb0, Qp);
  gemm512<<<512, 256, 0, stream>>>(Qp, To, cbo, nullptr, Qp, Kp);
  lnorm_out<<<4096, 256, 0, stream>>>(Kp, cg1, cb1, (float*)d_out);
}

// Round 8
// 281.752 us; speedup vs baseline: 1.1055x; 1.0136x over previous
//
#include <hip/hip_runtime.h>
#include <hip/hip_bf16.h>
#include <cstdint>

// ---------------------------------------------------------------------------
// MAB block (f32 in/out, bf16 internal):
//   Qp=(Q@Wq+bq)*Qm; Kp=(K@Wk+bk)*Km; V=K@Wv+bv
//   S = Qh Kh^T / sqrt(512);  X = exp(exp(S)*Km)*Qm;  A = X/(sum+1e-8)
//   O = Qh + A@Vh;  O = LN0(O);  O = O + relu(O@Wo+bo);  out = LN1(O)
//
// R9:  attn 2->4 blocks/CU. R10: FAILED reg-stage (spill). R11: setprio
//      HURT (lockstep). R12: f32A GEMM fusion (neutral). R13: kt-rotation
//      (-2%: convoy theory dead) + prep/proj merges (-5.6 total).
// R15: attn T3 2-phase pipeline + T21 swizzle:
//      - Kp/Vt written PRE-SWIZZLED by proj_all (col ^= (row&7)<<3 within
//        64-elem tile rows; free index math). Only attn reads them.
//      - attn stages K/V via global_load_lds (linear dest) into DOUBLE-
//        buffered sK/sVt[2][64][64]; reads use the XOR -> conflict-free.
//      - next tile issued BEFORE compute; ONE __syncthreads per kt (drains
//        vmcnt) -> staging latency hides under S^T+softmax+PV.
//      - Km pre-staged once as bf16 (exact 0/1); LOG2E folded into exp2
//        arg: e1L = exp2(s*c1 + log2(log2e)); y = exp2(e1L*km). Identical.
//      LDS 52.5KB -> 3 blocks/CU, launch_bounds(256,3).
// Buffers: ws ~36MB; d_out upper 16MB = Vt (dead before final LN writes).
// ---------------------------------------------------------------------------

typedef __bf16 bf16;
typedef __bf16 bf16x4 __attribute__((ext_vector_type(4)));
typedef __bf16 bf16x8 __attribute__((ext_vector_type(8)));
typedef float f32x4 __attribute__((ext_vector_type(4)));

#define MFMA16(a, b, c) __builtin_amdgcn_mfma_f32_16x16x32_bf16((a), (b), (c), 0, 0, 0)

#if __has_builtin(__builtin_amdgcn_exp2f)
#define EXP2F(x) __builtin_amdgcn_exp2f(x)
#else
#define EXP2F(x) exp2f(x)
#endif

static __device__ __forceinline__ void async_lds16(const bf16* g, bf16* l) {
  __builtin_amdgcn_global_load_lds(
      (__attribute__((address_space(1))) void*)(void*)g,
      (__attribute__((address_space(3))) void*)l,
      16, 0, 0);
}

// XCD swizzle for 512-block GEMM grids: 4 col-blocks of one row share id&7.
static __device__ __forceinline__ void swz512(int id, long& rowBase, int& colBase) {
  colBase = ((id >> 3) & 3) * 128;
  rowBase = (long)((id & 7) + 8 * (id >> 5)) * 128;
}

// ---------------------------------------------------------------------------
// Batched f32->bf16 conversion args (10 small arrays).
// ---------------------------------------------------------------------------
struct ConvArgs {
  const float* src[10];
  bf16* dst[10];
  int n[10];
};

// ---------------------------------------------------------------------------
// prep: ids 0..255 = weight transpose (4 x 512x512); 256..335 = converts.
// T[n][k] = (bf16)W[k][n].
// ---------------------------------------------------------------------------
__global__ __launch_bounds__(256) void prep(
    const float* __restrict__ Wq, const float* __restrict__ Wk,
    const float* __restrict__ Wv, const float* __restrict__ Wo,
    bf16* __restrict__ Tq, bf16* __restrict__ Tk,
    bf16* __restrict__ Tv, bf16* __restrict__ To, ConvArgs ca) {
  __shared__ bf16 t[64][72];
  const int id = blockIdx.x;
  const int tid = threadIdx.x;
  if (id < 256) {
    const int bx = id & 7, by = (id >> 3) & 7, bz = id >> 6;
    const float* src;
    bf16* dst;
    switch (bz) {
      case 0: src = Wq; dst = Tq; break;
      case 1: src = Wk; dst = Tk; break;
      case 2: src = Wv; dst = Tv; break;
      default: src = Wo; dst = To; break;
    }
    const int n0 = bx * 64;
    const int k0 = by * 64;
    for (int c = tid; c < 512; c += 256) {
      const int row = c >> 3, col = (c & 7) * 8;   // row: k, col: n
      const float* sp = src + (size_t)(k0 + row) * 512 + n0 + col;
      const f32x4 a = *(const f32x4*)sp;
      const f32x4 b = *(const f32x4*)(sp + 4);
      bf16x8 v;
#pragma unroll
      for (int j = 0; j < 4; ++j) { v[j] = (bf16)a[j]; v[j + 4] = (bf16)b[j]; }
      *(bf16x8*)(&t[row][col]) = v;
    }
    __syncthreads();
    for (int c = tid; c < 512; c += 256) {
      const int row = c >> 3, col8 = (c & 7) * 8;  // row: n, col8: k
      bf16x8 v;
#pragma unroll
      for (int j = 0; j < 8; ++j) v[j] = t[col8 + j][row];
      *(bf16x8*)(dst + (size_t)(n0 + row) * 512 + k0 + col8) = v;
    }
  } else {
    const int cid = id - 256;
    const int seg = cid >> 3;
    const int n = ca.n[seg];
    const long i = ((long)(cid & 7) * 256 + tid) * 8;
    if (i >= n) return;
    const float* s = ca.src[seg];
    const f32x4 x0 = *(const f32x4*)(s + i);
    const f32x4 x1 = *(const f32x4*)(s + i + 4);
    bf16x8 o;
#pragma unroll
    for (int j = 0; j < 4; ++j) { o[j] = (bf16)x0[j]; o[j + 4] = (bf16)x1[j]; }
    *(bf16x8*)(ca.dst[seg] + i) = o;
  }
}

// ---------------------------------------------------------------------------
// GEMM (bf16 A): out[M x 512] = epilogue(A @ Bt^T + bias).
//   mask != null : out = (acc+bias) * mask[row]
//   resid != null: out = resid + relu(acc+bias)
// ---------------------------------------------------------------------------
__global__ __launch_bounds__(256, 2) void gemm512(
    const bf16* __restrict__ A, const bf16* __restrict__ Bt,
    const bf16* __restrict__ bias, const bf16* __restrict__ mask,
    const bf16* __restrict__ resid, bf16* __restrict__ out) {
  __shared__ bf16 sA[128 * 32];
  __shared__ bf16 sB[128 * 32];
  const int tid = threadIdx.x;
  const int lane = tid & 63;
  const int w = tid >> 6;
  const int fm = lane & 15;
  const int fq = lane >> 4;
  long rowBase; int colBase;
  swz512(blockIdx.x, rowBase, colBase);

  f32x4 acc[4][4] = {};

  const int c0 = tid, c1 = tid + 256;
  const int r0 = c0 >> 2, o0 = (c0 & 3) * 8;
  const int r1 = c1 >> 2, o1 = (c1 & 3) * 8;
  const bf16* A0 = A + (rowBase + r0) * 512 + o0;
  const bf16* A1 = A + (rowBase + r1) * 512 + o1;
  const bf16* B0 = Bt + (size_t)(colBase + r0) * 512 + o0;
  const bf16* B1 = Bt + (size_t)(colBase + r1) * 512 + o1;

  const int wr = (w & 1) * 64;
  const int wc = (w >> 1) * 64;

  for (int kt = 0; kt < 16; ++kt) {
    const int k0 = kt * 32;
    __syncthreads();
    async_lds16(A0 + k0, sA + c0 * 8);
    async_lds16(A1 + k0, sA + c1 * 8);
    async_lds16(B0 + k0, sB + c0 * 8);
    async_lds16(B1 + k0, sB + c1 * 8);
    __syncthreads();
    bf16x8 a[4], b[4];
#pragma unroll
    for (int i = 0; i < 4; ++i)
      a[i] = *(const bf16x8*)(sA + (wr + i * 16 + fm) * 32 + fq * 8);
#pragma unroll
    for (int j = 0; j < 4; ++j)
      b[j] = *(const bf16x8*)(sB + (wc + j * 16 + fm) * 32 + fq * 8);
#pragma unroll
    for (int i = 0; i < 4; ++i)
#pragma unroll
      for (int j = 0; j < 4; ++j)
        acc[i][j] = MFMA16(a[i], b[j], acc[i][j]);
  }

  // epilogue; C/D layout: col = lane&15, row = (lane>>4)*4 + r
#pragma unroll
  for (int i = 0; i < 4; ++i) {
#pragma unroll
    for (int r = 0; r < 4; ++r) {
      const long R = rowBase + wr + i * 16 + fq * 4 + r;
      const float mk = mask ? (float)mask[R] : 1.0f;
      const bf16* resrow = resid ? resid + R * 512 : nullptr;
      bf16* outrow = out + R * 512;
#pragma unroll
      for (int j = 0; j < 4; ++j) {
        const int C = colBase + wc + j * 16 + fm;
        float v = acc[i][j][r] + (float)bias[C];
        if (mask) v *= mk;
        if (resid) v = (float)resrow[C] + fmaxf(v, 0.0f);
        outrow[C] = (bf16)v;
      }
    }
  }
}

// ---------------------------------------------------------------------------
// proj_all: ids 0..511 = Q projection (f32 A, fused cvt, T14 prefetch);
// ids 512..1023 = fused K/V projection.
// R15: Kp and Vt written PRE-SWIZZLED for attn's T21 staging:
//   Kp storage col = (C&~63) | ((C&63) ^ ((R&7)<<3))
//   Vt storage kk  = (kk&~63) | ((kk&63) ^ ((d&7)<<3))
// ---------------------------------------------------------------------------
__global__ __launch_bounds__(256, 2) void proj_all(
    const float* __restrict__ Qf, const float* __restrict__ Kf,
    const bf16* __restrict__ Tq, const bf16* __restrict__ Tk,
    const bf16* __restrict__ Tv, const bf16* __restrict__ bq,
    const bf16* __restrict__ bk, const bf16* __restrict__ bv,
    const bf16* __restrict__ Qm, const bf16* __restrict__ Km,
    bf16* __restrict__ Qp, bf16* __restrict__ Kp, bf16* __restrict__ Vt) {
  __shared__ bf16 sA[128 * 32];
  __shared__ bf16 sB1[128 * 32];
  __shared__ bf16 sB2[128 * 32];
  const int tid = threadIdx.x;
  const int lane = tid & 63;
  const int w = tid >> 6;
  const int fm = lane & 15;
  const int fq = lane >> 4;
  const int wr = (w & 1) * 64;
  const int wc = (w >> 1) * 64;
  const int c0 = tid, c1 = tid + 256;
  const int r0 = c0 >> 2, o0 = (c0 & 3) * 8;
  const int r1 = c1 >> 2, o1 = (c1 & 3) * 8;

  if (blockIdx.x < 512) {
    // ---- Q projection ----
    long rowBase; int colBase;
    swz512(blockIdx.x, rowBase, colBase);
    f32x4 acc[4][4] = {};
    const float* A0 = Qf + (rowBase + r0) * 512 + o0;
    const float* A1 = Qf + (rowBase + r1) * 512 + o1;
    const bf16* B0 = Tq + (size_t)(colBase + r0) * 512 + o0;
    const bf16* B1 = Tq + (size_t)(colBase + r1) * 512 + o1;

    f32x4 x0 = *(const f32x4*)(A0);
    f32x4 x1 = *(const f32x4*)(A0 + 4);
    f32x4 y0 = *(const f32x4*)(A1);
    f32x4 y1 = *(const f32x4*)(A1 + 4);

    for (int kt = 0; kt < 16; ++kt) {
      __syncthreads();
      async_lds16(B0 + kt * 32, sB1 + c0 * 8);
      async_lds16(B1 + kt * 32, sB1 + c1 * 8);
      {
        bf16x8 va, vb;
#pragma unroll
        for (int j = 0; j < 4; ++j) {
          va[j] = (bf16)x0[j]; va[j + 4] = (bf16)x1[j];
          vb[j] = (bf16)y0[j]; vb[j + 4] = (bf16)y1[j];
        }
        *(bf16x8*)(sA + c0 * 8) = va;
        *(bf16x8*)(sA + c1 * 8) = vb;
      }
      __syncthreads();
      if (kt < 15) {
        const int k1 = kt * 32 + 32;
        x0 = *(const f32x4*)(A0 + k1);
        x1 = *(const f32x4*)(A0 + k1 + 4);
        y0 = *(const f32x4*)(A1 + k1);
        y1 = *(const f32x4*)(A1 + k1 + 4);
      }
      bf16x8 a[4], b[4];
#pragma unroll
      for (int i = 0; i < 4; ++i)
        a[i] = *(const bf16x8*)(sA + (wr + i * 16 + fm) * 32 + fq * 8);
#pragma unroll
      for (int j = 0; j < 4; ++j)
        b[j] = *(const bf16x8*)(sB1 + (wc + j * 16 + fm) * 32 + fq * 8);
#pragma unroll
      for (int i = 0; i < 4; ++i)
#pragma unroll
        for (int j = 0; j < 4; ++j)
          acc[i][j] = MFMA16(a[i], b[j], acc[i][j]);
    }

#pragma unroll
    for (int i = 0; i < 4; ++i) {
#pragma unroll
      for (int r = 0; r < 4; ++r) {
        const long R = rowBase + wr + i * 16 + fq * 4 + r;
        const float mk = (float)Qm[R];
        bf16* outrow = Qp + R * 512;
#pragma unroll
        for (int j = 0; j < 4; ++j) {
          const int C = colBase + wc + j * 16 + fm;
          outrow[C] = (bf16)((acc[i][j][r] + (float)bq[C]) * mk);
        }
      }
    }
  } else {
    // ---- fused K/V projection ----
    long rowBase; int colBase;
    swz512(blockIdx.x - 512, rowBase, colBase);
    f32x4 acck[4][4] = {};
    f32x4 accv[4][4] = {};
    const float* A0 = Kf + (rowBase + r0) * 512 + o0;
    const float* A1 = Kf + (rowBase + r1) * 512 + o1;
    const bf16* Bk0 = Tk + (size_t)(colBase + r0) * 512 + o0;
    const bf16* Bk1 = Tk + (size_t)(colBase + r1) * 512 + o1;
    const bf16* Bv0 = Tv + (size_t)(colBase + r0) * 512 + o0;
    const bf16* Bv1 = Tv + (size_t)(colBase + r1) * 512 + o1;

    f32x4 x0 = *(const f32x4*)(A0);
    f32x4 x1 = *(const f32x4*)(A0 + 4);
    f32x4 y0 = *(const f32x4*)(A1);
    f32x4 y1 = *(const f32x4*)(A1 + 4);

    for (int kt = 0; kt < 16; ++kt) {
      const int k0 = kt * 32;
      __syncthreads();
      async_lds16(Bk0 + k0, sB1 + c0 * 8);
      async_lds16(Bk1 + k0, sB1 + c1 * 8);
      async_lds16(Bv0 + k0, sB2 + c0 * 8);
      async_lds16(Bv1 + k0, sB2 + c1 * 8);
      {
        bf16x8 va, vb;
#pragma unroll
        for (int j = 0; j < 4; ++j) {
          va[j] = (bf16)x0[j]; va[j + 4] = (bf16)x1[j];
          vb[j] = (bf16)y0[j]; vb[j + 4] = (bf16)y1[j];
        }
        *(bf16x8*)(sA + c0 * 8) = va;
        *(bf16x8*)(sA + c1 * 8) = vb;
      }
      __syncthreads();
      if (kt < 15) {
        const int k1 = k0 + 32;
        x0 = *(const f32x4*)(A0 + k1);
        x1 = *(const f32x4*)(A0 + k1 + 4);
        y0 = *(const f32x4*)(A1 + k1);
        y1 = *(const f32x4*)(A1 + k1 + 4);
      }
      bf16x8 a[4], b[4], bv2[4];
#pragma unroll
      for (int i = 0; i < 4; ++i)
        a[i] = *(const bf16x8*)(sA + (wr + i * 16 + fm) * 32 + fq * 8);
#pragma unroll
      for (int j = 0; j < 4; ++j) {
        b[j] = *(const bf16x8*)(sB1 + (wc + j * 16 + fm) * 32 + fq * 8);
        bv2[j] = *(const bf16x8*)(sB2 + (wc + j * 16 + fm) * 32 + fq * 8);
      }
#pragma unroll
      for (int i = 0; i < 4; ++i)
#pragma unroll
        for (int j = 0; j < 4; ++j) {
          acck[i][j] = MFMA16(a[i], b[j], acck[i][j]);
          accv[i][j] = MFMA16(a[i], bv2[j], accv[i][j]);
        }
    }

    const int bidx = (int)(rowBase >> 10);
#pragma unroll
    for (int i = 0; i < 4; ++i) {
#pragma unroll
      for (int r = 0; r < 4; ++r) {
        const long R = rowBase + wr + i * 16 + fq * 4 + r;
        const int rs = (int)(R & 7) << 3;      // attn-tile row swizzle
        const float mk = (float)Km[R];
        bf16* outrow = Kp + R * 512;
#pragma unroll
        for (int j = 0; j < 4; ++j) {
          const int C = colBase + wc + j * 16 + fm;
          const int Cs = (C & ~63) | ((C & 63) ^ rs);
          outrow[Cs] = (bf16)((acck[i][j][r] + (float)bk[C]) * mk);
        }
      }
      // V: transposed store, r -> 4 consecutive kk (8B store), swizzled kk
      const int kkb = (int)(rowBase & 1023) + wr + i * 16 + fq * 4;
#pragma unroll
      for (int j = 0; j < 4; ++j) {
        const int C = colBase + wc + j * 16 + fm;
        const int ds = (C & 7) << 3;           // d&7 == fm&7? C&7 covers it
        const int kks = (kkb & ~63) | ((kkb & 63) ^ ds);
        const float bvc = (float)bv[C];
        bf16x4 pv;
#pragma unroll
        for (int r = 0; r < 4; ++r) pv[r] = (bf16)(accv[i][j][r] + bvc);
        bf16* dst =
            Vt + ((size_t)(bidx * 8 + (C >> 6)) * 64 + (C & 63)) * 1024 + kks;
        *(bf16x4*)((void*)dst) = pv;
      }
    }
  }
}

// ---------------------------------------------------------------------------
// Attention R15: 128-q-row blocks, wave owns 32 q-rows. Grid 1024,
// id&7==h XCD locality; kt-rotation kept (rot=(id>>3)&15).
// T3 2-phase: double-buffered sK/sVt staged via global_load_lds from
// PRE-SWIZZLED Kp/Vt; next tile issued before compute; ONE barrier/kt.
// Reads XOR-swizzled: elem col ^= (row&7)<<3. Km staged once as bf16.
// y = exp2(exp2(s*c1 + C2)*km), C2 = log2(log2e). LDS 52.5KB, 3 blk/CU.
// ---------------------------------------------------------------------------
__global__ __launch_bounds__(256, 3) void attn_kernel(
    bf16* __restrict__ Qp, const bf16* __restrict__ Kp,
    const bf16* __restrict__ Vt, const bf16* __restrict__ Qm,
    const bf16* __restrict__ Km) {
  __shared__ bf16 sK[2][64][64];   // swizzled storage
  __shared__ bf16 sVt[2][64][64];
  __shared__ bf16 sX[4][32][72];   // per-wave [q][kk]
  __shared__ bf16 sKm[1024];       // whole-batch K mask (exact 0/1)
  __shared__ float sL[4][32];

  const int tid = threadIdx.x;
  const int lane = tid & 63;
  const int w = tid >> 6;
  const int fm = lane & 15;
  const int fq = lane >> 4;
  const int id = blockIdx.x;
  const int bh = id & 127;
  const int q0 = (id >> 7) * 128;
  const int b = bh >> 3;
  const int hh = bh & 7;
  const int rot = (id >> 3) & 15;

  bf16* Qbase = Qp + ((long)b * 1024 + q0) * 512 + hh * 64;
  float qm_lane[2];
  qm_lane[0] = (float)Qm[(long)b * 1024 + q0 + w * 32 + fm];
  qm_lane[1] = (float)Qm[(long)b * 1024 + q0 + w * 32 + 16 + fm];

  // loop-invariant Q fragments straight from global: [subtile u][ks]
  bf16x8 qf[2][2];
#pragma unroll
  for (int u = 0; u < 2; ++u)
#pragma unroll
    for (int ks = 0; ks < 2; ++ks)
      qf[u][ks] = *(const bf16x8*)(Qbase + (long)(w * 32 + u * 16 + fm) * 512 +
                                   ks * 32 + fq * 8);

  f32x4 acc_o[2][4] = {};
  float l_lane[2] = {0.f, 0.f};
  const float c1 = 0.063758715f;       // log2(e)/sqrt(512)
  const float C2 = 0.5287663729448977f;  // log2(log2(e))

  const bf16* Vthead = Vt + ((long)b * 8 + hh) * 64 * 1024;  // [d][kk] swz
  const bf16* Kbb = Kp + (long)b * 1024 * 512 + hh * 64;     // swz cols
  const bf16* Kmb = Km + (long)b * 1024;

  const int srow = tid >> 3;           // 0..31
  const int scol = (tid & 7) * 8;
  const int xsw = (fm & 7) << 3;       // read-side swizzle

  // prologue: stage tile 0 + whole Km
  {
    const int kk0 = (rot & 15) * 64;
    const bf16* Kb0 = Kbb + (long)kk0 * 512;
    async_lds16(Kb0 + (long)srow * 512 + scol, &sK[0][0][0] + tid * 8);
    async_lds16(Kb0 + (long)(srow + 32) * 512 + scol,
                &sK[0][0][0] + 2048 + tid * 8);
    async_lds16(Vthead + (long)srow * 1024 + kk0 + scol, &sVt[0][0][0] + tid * 8);
    async_lds16(Vthead + (long)(srow + 32) * 1024 + kk0 + scol,
                &sVt[0][0][0] + 2048 + tid * 8);
    *(bf16x4*)(&sKm[tid * 4]) = *(const bf16x4*)(Kmb + tid * 4);
  }
  __syncthreads();

  for (int kt = 0; kt < 16; ++kt) {
    const int cur = kt & 1;
    // issue next tile's DMA before compute (drains at end-of-kt barrier)
    if (kt < 15) {
      const int kk1 = ((kt + 1 + rot) & 15) * 64;
      const bf16* Kb1 = Kbb + (long)kk1 * 512;
      bf16* dK = &sK[cur ^ 1][0][0];
      bf16* dV = &sVt[cur ^ 1][0][0];
      async_lds16(Kb1 + (long)srow * 512 + scol, dK + tid * 8);
      async_lds16(Kb1 + (long)(srow + 32) * 512 + scol, dK + 2048 + tid * 8);
      async_lds16(Vthead + (long)srow * 1024 + kk1 + scol, dV + tid * 8);
      async_lds16(Vthead + (long)(srow + 32) * 1024 + kk1 + scol,
                  dV + 2048 + tid * 8);
    }
    const int kkT = ((kt + rot) & 15) * 64;

    // S^T: C[kk 64][q 32]; A = K rows (m=kk), B = Q rows (n=q, 2 subtiles)
    f32x4 s_acc[2][4] = {};
#pragma unroll
    for (int ks = 0; ks < 2; ++ks) {
      const int kc = (ks * 32 + fq * 8) ^ xsw;
#pragma unroll
      for (int t = 0; t < 4; ++t) {
        const bf16x8 kf = *(const bf16x8*)(&sK[cur][t * 16 + fm][kc]);
        s_acc[0][t] = MFMA16(kf, qf[0][ks], s_acc[0][t]);
        s_acc[1][t] = MFMA16(kf, qf[1][ks], s_acc[1][t]);
      }
    }
    // softmax: lane holds q=fm (subtile u), kk = t*16 + fq*4 + r
#pragma unroll
    for (int t = 0; t < 4; ++t) {
      const bf16x4 km4 = *(const bf16x4*)(&sKm[kkT + t * 16 + fq * 4]);
      float kmf[4];
#pragma unroll
      for (int r = 0; r < 4; ++r) kmf[r] = (float)km4[r];
#pragma unroll
      for (int u = 0; u < 2; ++u) {
        bf16x4 xp;
#pragma unroll
        for (int r = 0; r < 4; ++r) {
          const float e1L = EXP2F(fmaf(s_acc[u][t][r], c1, C2));
          const float y = EXP2F(e1L * kmf[r]);
          l_lane[u] += y;
          xp[r] = (bf16)y;
        }
        *(bf16x4*)((void*)&sX[w][u * 16 + fm][t * 16 + fq * 4]) = xp;
      }
    }
    // PV: C[q 32][d 64]; A = sX rows (2 subtiles), B = sVt rows (shared)
#pragma unroll
    for (int ks = 0; ks < 2; ++ks) {
      const int kc = (ks * 32 + fq * 8) ^ xsw;
      const bf16x8 xf0 = *(const bf16x8*)(&sX[w][fm][ks * 32 + fq * 8]);
      const bf16x8 xf1 = *(const bf16x8*)(&sX[w][16 + fm][ks * 32 + fq * 8]);
#pragma unroll
      for (int t = 0; t < 4; ++t) {
        const bf16x8 vf = *(const bf16x8*)(&sVt[cur][t * 16 + fm][kc]);
        acc_o[0][t] = MFMA16(xf0, vf, acc_o[0][t]);
        acc_o[1][t] = MFMA16(xf1, vf, acc_o[1][t]);
      }
    }
    __syncthreads();   // drains next-tile DMA; frees cur buf for kt+2
  }

  // per-q Y-sums
#pragma unroll
  for (int u = 0; u < 2; ++u) {
    l_lane[u] += __shfl_xor(l_lane[u], 16);
    l_lane[u] += __shfl_xor(l_lane[u], 32);
    if (fq == 0) sL[w][u * 16 + fm] = l_lane[u];
  }
  __syncthreads();

  // epilogue: lane holds q = u*16 + fq*4 + r, d = t*16 + fm (PV C-layout)
#pragma unroll
  for (int u = 0; u < 2; ++u) {
#pragma unroll
    for (int t = 0; t < 4; ++t) {
#pragma unroll
      for (int r = 0; r < 4; ++r) {
        const int qr = w * 32 + u * 16 + fq * 4 + r;
        const int dc = t * 16 + fm;
        const float qm_r = __shfl(qm_lane[u], fq * 4 + r, 64);
        const float li = 1.0f / (qm_r * sL[w][u * 16 + fq * 4 + r] + 1e-8f);
        const float val =
            (float)Qbase[(long)qr * 512 + dc] + qm_r * acc_o[u][t][r] * li;
        Qbase[(long)qr * 512 + dc] = (bf16)val;
      }
    }
  }
}

// ---------------------------------------------------------------------------
// LayerNorm (bf16 -> bf16). One wave per row. In-place safe.
// ---------------------------------------------------------------------------
__global__ __launch_bounds__(256) void lnorm(
    const bf16* __restrict__ X, const bf16* __restrict__ g,
    const bf16* __restrict__ bb, bf16* __restrict__ out) {
  const int row = blockIdx.x * 4 + (threadIdx.x >> 6);
  const int lane = threadIdx.x & 63;
  const bf16x8 v = *(const bf16x8*)(X + (size_t)row * 512 + lane * 8);
  float x[8], s = 0.f, ss = 0.f;
#pragma unroll
  for (int j = 0; j < 8; ++j) {
    x[j] = (float)v[j];
    s += x[j];
    ss += x[j] * x[j];
  }
#pragma unroll
  for (int m = 1; m < 64; m <<= 1) {
    s += __shfl_xor(s, m);
    ss += __shfl_xor(ss, m);
  }
  const float mean = s * (1.0f / 512.0f);
  const float var = ss * (1.0f / 512.0f) - mean * mean;
  const float rstd = 1.0f / sqrtf(var + 1e-5f);
  const bf16x8 gv = *(const bf16x8*)(g + lane * 8);
  const bf16x8 bv = *(const bf16x8*)(bb + lane * 8);
  bf16x8 o;
#pragma unroll
  for (int j = 0; j < 8; ++j)
    o[j] = (bf16)((x[j] - mean) * rstd * (float)gv[j] + (float)bv[j]);
  *(bf16x8*)(out + (size_t)row * 512 + lane * 8) = o;
}

// ---------------------------------------------------------------------------
// Final LayerNorm: bf16 in, f32 out.
// ---------------------------------------------------------------------------
__global__ __launch_bounds__(256) void lnorm_out(
    const bf16* __restrict__ X, const bf16* __restrict__ g,
    const bf16* __restrict__ bb, float* __restrict__ out) {
  const int row = blockIdx.x * 4 + (threadIdx.x >> 6);
  const int lane = threadIdx.x & 63;
  const bf16x8 v = *(const bf16x8*)(X + (size_t)row * 512 + lane * 8);
  float x[8], s = 0.f, ss = 0.f;
#pragma unroll
  for (int j = 0; j < 8; ++j) {
    x[j] = (float)v[j];
    s += x[j];
    ss += x[j] * x[j];
  }
#pragma unroll
  for (int m = 1; m < 64; m <<= 1) {
    s += __shfl_xor(s, m);
    ss += __shfl_xor(ss, m);
  }
  const float mean = s * (1.0f / 512.0f);
  const float var = ss * (1.0f / 512.0f) - mean * mean;
  const float rstd = 1.0f / sqrtf(var + 1e-5f);
  const bf16x8 gv = *(const bf16x8*)(g + lane * 8);
  const bf16x8 bv = *(const bf16x8*)(bb + lane * 8);
  f32x4 a, c;
#pragma unroll
  for (int j = 0; j < 4; ++j) {
    a[j] = (x[j] - mean) * rstd * (float)gv[j] + (float)bv[j];
    c[j] = (x[j + 4] - mean) * rstd * (float)gv[j + 4] + (float)bv[j + 4];
  }
  float* fo = out + (size_t)row * 512 + lane * 8;
  *(f32x4*)fo = a;
  *(f32x4*)(fo + 4) = c;
}

// ---------------------------------------------------------------------------
extern "C" void kernel_launch(void* const* d_in, const int* in_sizes, int n_in,
                              void* d_out, int out_size, void* d_ws, size_t ws_size,
                              hipStream_t stream) {
  (void)in_sizes; (void)n_in; (void)out_size; (void)ws_size;
  const float* Q = (const float*)d_in[0];
  const float* K = (const float*)d_in[1];

  bf16* ws = (bf16*)d_ws;
  const long W2 = 512L * 512;
  const long MN = 16384L * 512;
  bf16* Tq = ws;                           // 4 transposed bf16 weights: 2MB
  bf16* Tk = Tq + W2;
  bf16* Tv = Tk + W2;
  bf16* To = Tv + W2;
  bf16* sm = To + W2;                      // 8 x 512 smalls
  bf16* cQm = sm + 8 * 512;                // 16384
  bf16* cKm = cQm + 16384;                 // 16384
  bf16* Qp = cKm + 16384;                  // 16MB
  bf16* Kp = Qp + MN;                      // 16MB
  bf16* Vt = (bf16*)d_out + MN;            // V^T in d_out upper 16MB

  bf16* cbq = sm + 0 * 512;
  bf16* cbk = sm + 1 * 512;
  bf16* cbv = sm + 2 * 512;
  bf16* cbo = sm + 3 * 512;
  bf16* cg0 = sm + 4 * 512;
  bf16* cb0 = sm + 5 * 512;
  bf16* cg1 = sm + 6 * 512;
  bf16* cb1 = sm + 7 * 512;

  ConvArgs ca;
  ca.src[0] = (const float*)d_in[2];  ca.dst[0] = cQm; ca.n[0] = 16384;
  ca.src[1] = (const float*)d_in[3];  ca.dst[1] = cKm; ca.n[1] = 16384;
  ca.src[2] = (const float*)d_in[5];  ca.dst[2] = cbq; ca.n[2] = 512;
  ca.src[3] = (const float*)d_in[7];  ca.dst[3] = cbk; ca.n[3] = 512;
  ca.src[4] = (const float*)d_in[9];  ca.dst[4] = cbv; ca.n[4] = 512;
  ca.src[5] = (const float*)d_in[11]; ca.dst[5] = cbo; ca.n[5] = 512;
  ca.src[6] = (const float*)d_in[12]; ca.dst[6] = cg0; ca.n[6] = 512;
  ca.src[7] = (const float*)d_in[13]; ca.dst[7] = cb0; ca.n[7] = 512;
  ca.src[8] = (const float*)d_in[14]; ca.dst[8] = cg1; ca.n[8] = 512;
  ca.src[9] = (const float*)d_in[15]; ca.dst[9] = cb1; ca.n[9] = 512;

  prep<<<336, 256, 0, stream>>>(
      (const float*)d_in[4], (const float*)d_in[6],
      (const float*)d_in[8], (const float*)d_in[10], Tq, Tk, Tv, To, ca);

  proj_all<<<1024, 256, 0, stream>>>(Q, K, Tq, Tk, Tv, cbq, cbk, cbv,
                                     cQm, cKm, Qp, Kp, Vt);

  attn_kernel<<<1024, 256, 0, stream>>>(Qp, Kp, Vt, cQm, cKm);

  lnorm<<<4096, 256, 0, stream>>>(Qp, cg0, cb0, Qp);
  gemm512<<<512, 256, 0, stream>>>(Qp, To, cbo, nullptr, Qp, Kp);
  lnorm_out<<<4096, 256, 0, stream>>>(Kp, cg1, cb1, (float*)d_out);
}